// Round 2
// baseline (6497.889 us; speedup 1.0000x reference)
//
#include <hip/hip_runtime.h>
#include <math.h>
#include <stddef.h>

#define B_ 2
#define N_ 2048
#define DM 2048
#define H_ 16
#define HD 128
#define INNER 2048
#define TRIPLE 6144
#define M_ (B_ * N_)   // 4096
#define RC 4           // row chunks in recurrence
#define ROWS 32        // rows per recurrence block

__device__ __forceinline__ float sig_(float x) { return 1.0f / (1.0f + __expf(-x)); }

// C[m,n] = sum_k A[m,k] * W[n,k]  (+bias, +activation)
// act: 0 = none, 1 = silu, 2 = sigmoid
__global__ __launch_bounds__(256) void gemm_bt_f32(
    const float* __restrict__ A, const float* __restrict__ W,
    const float* __restrict__ bias, float* __restrict__ C,
    int M, int Nn, int K, int act)
{
    __shared__ float As[16][72];  // [k][m], stride 72 floats
    __shared__ float Bs[16][72];  // [k][n]
    const int tid = threadIdx.x;
    const int tx = tid & 15, ty = tid >> 4;
    const int col0 = blockIdx.x * 64;
    const int row0 = blockIdx.y * 64;
    const int lr = tid >> 2;        // 0..63: row within tile for loading
    const int lk = (tid & 3) * 4;   // k offset 0,4,8,12

    float acc[4][4];
#pragma unroll
    for (int i = 0; i < 4; ++i)
#pragma unroll
        for (int j = 0; j < 4; ++j) acc[i][j] = 0.f;

    const float* Arow = A + (size_t)(row0 + lr) * K;
    const float* Wrow = W + (size_t)(col0 + lr) * K;
    const bool wvalid = (col0 + lr) < Nn;

    for (int k0 = 0; k0 < K; k0 += 16) {
        float4 a4 = *(const float4*)(Arow + k0 + lk);
        float4 b4 = wvalid ? *(const float4*)(Wrow + k0 + lk) : make_float4(0.f, 0.f, 0.f, 0.f);
        __syncthreads();
        As[lk + 0][lr] = a4.x; As[lk + 1][lr] = a4.y; As[lk + 2][lr] = a4.z; As[lk + 3][lr] = a4.w;
        Bs[lk + 0][lr] = b4.x; Bs[lk + 1][lr] = b4.y; Bs[lk + 2][lr] = b4.z; Bs[lk + 3][lr] = b4.w;
        __syncthreads();
#pragma unroll
        for (int kk = 0; kk < 16; ++kk) {
            float4 av = *(const float4*)&As[kk][ty * 4];
            float4 bv = *(const float4*)&Bs[kk][tx * 4];
            acc[0][0] += av.x * bv.x; acc[0][1] += av.x * bv.y; acc[0][2] += av.x * bv.z; acc[0][3] += av.x * bv.w;
            acc[1][0] += av.y * bv.x; acc[1][1] += av.y * bv.y; acc[1][2] += av.y * bv.z; acc[1][3] += av.y * bv.w;
            acc[2][0] += av.z * bv.x; acc[2][1] += av.z * bv.y; acc[2][2] += av.z * bv.z; acc[2][3] += av.z * bv.w;
            acc[3][0] += av.w * bv.x; acc[3][1] += av.w * bv.y; acc[3][2] += av.w * bv.z; acc[3][3] += av.w * bv.w;
        }
    }

#pragma unroll
    for (int i = 0; i < 4; ++i) {
        int r = row0 + ty * 4 + i;
#pragma unroll
        for (int j = 0; j < 4; ++j) {
            int c = col0 + tx * 4 + j;
            if (c < Nn) {
                float v = acc[i][j];
                if (bias) v += bias[c];
                if (act == 1) v = v * sig_(v);
                else if (act == 2) v = sig_(v);
                C[(size_t)r * Nn + c] = v;
            }
        }
    }
}

// Per-token: depthwise causal conv (K=4) + silu over 6144 channels, then
// L2-normalize q (ch 0..2047) and k (ch 2048..4095) per head of 128.
__global__ __launch_bounds__(256) void conv_silu_norm(
    const float* __restrict__ qkv, const float* __restrict__ conv_w,
    float* __restrict__ outb)
{
    __shared__ float buf[TRIPLE];
    __shared__ float scales[32];
    const int bn = blockIdx.x;       // b*N + n
    const int n = bn & (N_ - 1);
    const int tid = threadIdx.x;
    const float* base = qkv + (size_t)bn * TRIPLE;

    for (int c = tid; c < TRIPLE; c += 256) {
        float acc = 0.f;
#pragma unroll
        for (int j = 0; j < 4; ++j) {
            int nn = n - 3 + j;
            float xv = (nn >= 0) ? base[(ptrdiff_t)(j - 3) * TRIPLE + c] : 0.f;
            acc += xv * conv_w[c * 4 + j];
        }
        buf[c] = acc * sig_(acc);
    }
    __syncthreads();

    // 32 norm groups (16 q heads + 16 k heads), 8 threads each
    const int g = tid >> 3, l = tid & 7;
    {
        int off = (g < 16) ? g * HD : 2048 + (g - 16) * HD;
        float s = 0.f;
        for (int i = l; i < HD; i += 8) { float v = buf[off + i]; s += v * v; }
        s += __shfl_xor(s, 1); s += __shfl_xor(s, 2); s += __shfl_xor(s, 4);
        if (l == 0) scales[g] = 1.0f / fmaxf(sqrtf(s), 1e-12f);
    }
    __syncthreads();

    float* ob = outb + (size_t)bn * TRIPLE;
    for (int c = tid; c < TRIPLE; c += 256) {
        float sc = 1.f;
        if (c < 2048) sc = scales[c >> 7];
        else if (c < 4096) sc = scales[16 + ((c - 2048) >> 7)];
        ob[c] = buf[c] * sc;
    }
}

// Delta-rule recurrence. Grid = B*H*RC blocks; each block owns ROWS=32 rows of
// the 128x128 state for one (b,h). Thread t: row = rc*32 + t/8, cols (t&7)*16..+16
// (16 state elements in registers). Dot reductions via shfl_xor over 8 lanes.
__global__ __launch_bounds__(256) void recurrence(
    const float* __restrict__ qkvc, const float* __restrict__ absig,
    const float* __restrict__ gpre, float* __restrict__ og)
{
    __shared__ float kq[256];   // [0:128)=k_t, [128:256)=q_t
    __shared__ float vv[ROWS];
    __shared__ float ab2[2];
    const int blk = blockIdx.x;
    const int rc = blk & (RC - 1);
    const int h  = (blk >> 2) & (H_ - 1);
    const int b  = blk >> 6;            // / (RC*H_)
    const int tid = threadIdx.x;
    const int r  = rc * ROWS + (tid >> 3);
    const int cb = (tid & 7) * 16;

    float s[16];
#pragma unroll
    for (int i = 0; i < 16; ++i) s[i] = 0.f;

    const float* qb  = qkvc + (size_t)b * N_ * TRIPLE + h * HD;
    const float* abb = absig + (size_t)b * N_ * 32;

    for (int n = 0; n < N_; ++n) {
        const float* qt = qb + (size_t)n * TRIPLE;
        if (tid < 128)      kq[tid] = qt[2048 + tid];       // k_t
        else                kq[tid] = qt[tid - 128];        // q_t
        if (tid < ROWS)     vv[tid] = qt[4096 + rc * ROWS + tid];
        if (tid == 0) { ab2[0] = abb[n * 32 + h]; ab2[1] = abb[n * 32 + 16 + h]; }
        __syncthreads();

        const float a = ab2[0], bt = ab2[1];
        float dot = 0.f;
#pragma unroll
        for (int i = 0; i < 16; ++i) dot += s[i] * kq[cb + i];
        dot += __shfl_xor(dot, 1); dot += __shfl_xor(dot, 2); dot += __shfl_xor(dot, 4);

        const float u = bt * (vv[tid >> 3] - a * dot);
        float od = 0.f;
#pragma unroll
        for (int i = 0; i < 16; ++i) {
            float sv = a * s[i] + u * kq[cb + i];
            s[i] = sv;
            od += sv * kq[128 + cb + i];
        }
        od += __shfl_xor(od, 1); od += __shfl_xor(od, 2); od += __shfl_xor(od, 4);

        if ((tid & 7) == 0) {
            size_t idx = ((size_t)b * N_ + n) * INNER + h * HD + r;
            og[idx] = od * gpre[idx];   // gpre already holds silu(x@W_g^T)
        }
        __syncthreads();
    }
}

extern "C" void kernel_launch(void* const* d_in, const int* in_sizes, int n_in,
                              void* d_out, int out_size, void* d_ws, size_t ws_size,
                              hipStream_t stream) {
    const float* x      = (const float*)d_in[0];
    const float* W_qkv  = (const float*)d_in[1];
    const float* conv_w = (const float*)d_in[2];
    const float* W_ab   = (const float*)d_in[3];
    const float* b_ab   = (const float*)d_in[4];
    const float* W_g    = (const float*)d_in[5];
    const float* W_o    = (const float*)d_in[6];
    float* out = (float*)d_out;

    // Workspace layout (floats). og ALIASES qkv_pre: qkv_pre is dead after
    // conv_silu_norm completes, and the stream serializes kernels.
    // Total: (2*M_*TRIPLE + M_*32 + M_*INNER)*4B = 235.5 MB.
    float* qkv_pre = (float*)d_ws;                          // M_*TRIPLE
    float* qkv_c   = qkv_pre + (size_t)M_ * TRIPLE;         // M_*TRIPLE
    float* absig   = qkv_c   + (size_t)M_ * TRIPLE;         // M_*32
    float* gpre    = absig   + (size_t)M_ * 32;             // M_*INNER
    float* og      = qkv_pre;                               // alias (M_*INNER <= M_*TRIPLE)

    dim3 blk(256);
    // qkv = x @ W_qkv^T
    gemm_bt_f32<<<dim3(TRIPLE / 64, M_ / 64), blk, 0, stream>>>(x, W_qkv, nullptr, qkv_pre, M_, TRIPLE, DM, 0);
    // alpha,beta = sigmoid(x @ W_ab^T + b_ab)
    gemm_bt_f32<<<dim3(1, M_ / 64), blk, 0, stream>>>(x, W_ab, b_ab, absig, M_, 32, DM, 2);
    // g = silu(x @ W_g^T)
    gemm_bt_f32<<<dim3(INNER / 64, M_ / 64), blk, 0, stream>>>(x, W_g, nullptr, gpre, M_, INNER, DM, 1);
    // conv + silu + l2norm(q,k)
    conv_silu_norm<<<dim3(B_ * N_), blk, 0, stream>>>(qkv_pre, conv_w, qkv_c);
    // delta-rule recurrence + gating (og overwrites qkv_pre — safe, serialized)
    recurrence<<<dim3(B_ * H_ * RC), blk, 0, stream>>>(qkv_c, absig, gpre, og);
    // y = (o*g) @ W_o^T
    gemm_bt_f32<<<dim3(INNER / 64, M_ / 64), blk, 0, stream>>>(og, W_o, nullptr, out, M_, INNER, DM, 0);
}

// Round 3
// 4993.744 us; speedup vs baseline: 1.3012x; 1.3012x over previous
//
#include <hip/hip_runtime.h>
#include <math.h>
#include <stddef.h>

#define B_ 2
#define N_ 2048
#define DM 2048
#define H_ 16
#define HD 128
#define INNER 2048
#define TRIPLE 6144
#define M_ (B_ * N_)   // 4096

__device__ __forceinline__ float sig_(float x) { return 1.0f / (1.0f + __expf(-x)); }

// C[m,n] = sum_k A[m,k] * W[n,k]  (+bias, +activation)
// act: 0 = none, 1 = silu, 2 = sigmoid
__global__ __launch_bounds__(256) void gemm_bt_f32(
    const float* __restrict__ A, const float* __restrict__ W,
    const float* __restrict__ bias, float* __restrict__ C,
    int M, int Nn, int K, int act)
{
    __shared__ float As[16][72];
    __shared__ float Bs[16][72];
    const int tid = threadIdx.x;
    const int tx = tid & 15, ty = tid >> 4;
    const int col0 = blockIdx.x * 64;
    const int row0 = blockIdx.y * 64;
    const int lr = tid >> 2;
    const int lk = (tid & 3) * 4;

    float acc[4][4];
#pragma unroll
    for (int i = 0; i < 4; ++i)
#pragma unroll
        for (int j = 0; j < 4; ++j) acc[i][j] = 0.f;

    const float* Arow = A + (size_t)(row0 + lr) * K;
    const float* Wrow = W + (size_t)(col0 + lr) * K;
    const bool wvalid = (col0 + lr) < Nn;

    for (int k0 = 0; k0 < K; k0 += 16) {
        float4 a4 = *(const float4*)(Arow + k0 + lk);
        float4 b4 = wvalid ? *(const float4*)(Wrow + k0 + lk) : make_float4(0.f, 0.f, 0.f, 0.f);
        __syncthreads();
        As[lk + 0][lr] = a4.x; As[lk + 1][lr] = a4.y; As[lk + 2][lr] = a4.z; As[lk + 3][lr] = a4.w;
        Bs[lk + 0][lr] = b4.x; Bs[lk + 1][lr] = b4.y; Bs[lk + 2][lr] = b4.z; Bs[lk + 3][lr] = b4.w;
        __syncthreads();
#pragma unroll
        for (int kk = 0; kk < 16; ++kk) {
            float4 av = *(const float4*)&As[kk][ty * 4];
            float4 bv = *(const float4*)&Bs[kk][tx * 4];
            acc[0][0] += av.x * bv.x; acc[0][1] += av.x * bv.y; acc[0][2] += av.x * bv.z; acc[0][3] += av.x * bv.w;
            acc[1][0] += av.y * bv.x; acc[1][1] += av.y * bv.y; acc[1][2] += av.y * bv.z; acc[1][3] += av.y * bv.w;
            acc[2][0] += av.z * bv.x; acc[2][1] += av.z * bv.y; acc[2][2] += av.z * bv.z; acc[2][3] += av.z * bv.w;
            acc[3][0] += av.w * bv.x; acc[3][1] += av.w * bv.y; acc[3][2] += av.w * bv.z; acc[3][3] += av.w * bv.w;
        }
    }

#pragma unroll
    for (int i = 0; i < 4; ++i) {
        int r = row0 + ty * 4 + i;
#pragma unroll
        for (int j = 0; j < 4; ++j) {
            int c = col0 + tx * 4 + j;
            if (c < Nn) {
                float v = acc[i][j];
                if (bias) v += bias[c];
                if (act == 1) v = v * sig_(v);
                else if (act == 2) v = sig_(v);
                C[(size_t)r * Nn + c] = v;
            }
        }
    }
}

__global__ __launch_bounds__(256) void conv_silu_norm(
    const float* __restrict__ qkv, const float* __restrict__ conv_w,
    float* __restrict__ outb)
{
    __shared__ float buf[TRIPLE];
    __shared__ float scales[32];
    const int bn = blockIdx.x;
    const int n = bn & (N_ - 1);
    const int tid = threadIdx.x;
    const float* base = qkv + (size_t)bn * TRIPLE;

    for (int c = tid; c < TRIPLE; c += 256) {
        float acc = 0.f;
#pragma unroll
        for (int j = 0; j < 4; ++j) {
            int nn = n - 3 + j;
            float xv = (nn >= 0) ? base[(ptrdiff_t)(j - 3) * TRIPLE + c] : 0.f;
            acc += xv * conv_w[c * 4 + j];
        }
        buf[c] = acc * sig_(acc);
    }
    __syncthreads();

    const int g = tid >> 3, l = tid & 7;
    {
        int off = (g < 16) ? g * HD : 2048 + (g - 16) * HD;
        float s = 0.f;
        for (int i = l; i < HD; i += 8) { float v = buf[off + i]; s += v * v; }
        s += __shfl_xor(s, 1); s += __shfl_xor(s, 2); s += __shfl_xor(s, 4);
        if (l == 0) scales[g] = 1.0f / fmaxf(sqrtf(s), 1e-12f);
    }
    __syncthreads();

    float* ob = outb + (size_t)bn * TRIPLE;
    for (int c = tid; c < TRIPLE; c += 256) {
        float sc = 1.f;
        if (c < 2048) sc = scales[c >> 7];
        else if (c < 4096) sc = scales[16 + ((c - 2048) >> 7)];
        ob[c] = buf[c] * sc;
    }
}

// Delta-rule recurrence, barrier-free.
// Each 32-lane half-wave owns ONE state row (128 cols, 4 floats/lane).
// Grid: 512 blocks x 256 thr = 2048 waves; 16 blocks per (b,h), 8 rows/block.
// Dot-reductions: 5x shfl_xor (masks 1..16 stay inside the 32-lane half).
// 1-token software-pipeline prefetch hides L2 latency. No LDS, no barriers.
__global__ __launch_bounds__(256) void recurrence(
    const float* __restrict__ qkvc, const float* __restrict__ absig,
    const float* __restrict__ gpre, float* __restrict__ og)
{
    const int blk  = blockIdx.x;          // 0..511
    const int bh   = blk >> 4;            // 0..31
    const int b    = bh >> 4;
    const int h    = bh & (H_ - 1);
    const int rblk = blk & 15;            // 8 rows per block
    const int tid  = threadIdx.x;
    const int wave = tid >> 6;
    const int lane = tid & 63;
    const int half = lane >> 5;
    const int lc   = lane & 31;
    const int row  = rblk * 8 + wave * 2 + half;   // 0..127
    const int c    = lc * 4;                       // column base

    const size_t tokbase = (size_t)b * N_ * TRIPLE;
    const float* qbase = qkvc + tokbase + h * HD;           // q
    const float* kbase = qkvc + tokbase + 2048 + h * HD;    // k
    const float* vbase = qkvc + tokbase + 4096 + h * HD;    // v
    const float* abb   = absig + (size_t)b * N_ * 32;

    float4 s = make_float4(0.f, 0.f, 0.f, 0.f);

    // preload token 0
    float4 k4 = *(const float4*)(kbase + c);
    float4 q4 = *(const float4*)(qbase + c);
    float  vr = vbase[row];
    float  a  = abb[h];
    float  bt = abb[16 + h];

    for (int n = 0; n < N_; ++n) {
        // issue next token's loads (independent of current compute)
        const int np = (n + 1 < N_) ? n + 1 : n;
        const size_t noff = (size_t)np * TRIPLE;
        float4 k4n = *(const float4*)(kbase + noff + c);
        float4 q4n = *(const float4*)(qbase + noff + c);
        float  vrn = vbase[noff + row];
        float  an  = abb[np * 32 + h];
        float  btn = abb[np * 32 + 16 + h];

        // Sk (row dot)
        float dot = s.x * k4.x + s.y * k4.y + s.z * k4.z + s.w * k4.w;
        dot += __shfl_xor(dot, 1);  dot += __shfl_xor(dot, 2);
        dot += __shfl_xor(dot, 4);  dot += __shfl_xor(dot, 8);
        dot += __shfl_xor(dot, 16);

        const float u = bt * (vr - a * dot);
        s.x = a * s.x + u * k4.x;
        s.y = a * s.y + u * k4.y;
        s.z = a * s.z + u * k4.z;
        s.w = a * s.w + u * k4.w;

        float od = s.x * q4.x + s.y * q4.y + s.z * q4.z + s.w * q4.w;
        od += __shfl_xor(od, 1);  od += __shfl_xor(od, 2);
        od += __shfl_xor(od, 4);  od += __shfl_xor(od, 8);
        od += __shfl_xor(od, 16);

        if (lc == 0) {
            size_t idx = ((size_t)b * N_ + n) * INNER + h * HD + row;
            og[idx] = od * gpre[idx];
        }

        k4 = k4n; q4 = q4n; vr = vrn; a = an; bt = btn;
    }
}

extern "C" void kernel_launch(void* const* d_in, const int* in_sizes, int n_in,
                              void* d_out, int out_size, void* d_ws, size_t ws_size,
                              hipStream_t stream) {
    const float* x      = (const float*)d_in[0];
    const float* W_qkv  = (const float*)d_in[1];
    const float* conv_w = (const float*)d_in[2];
    const float* W_ab   = (const float*)d_in[3];
    const float* b_ab   = (const float*)d_in[4];
    const float* W_g    = (const float*)d_in[5];
    const float* W_o    = (const float*)d_in[6];
    float* out = (float*)d_out;

    // ws: og aliases qkv_pre (dead after conv_silu_norm; stream serializes).
    float* qkv_pre = (float*)d_ws;                          // M_*TRIPLE
    float* qkv_c   = qkv_pre + (size_t)M_ * TRIPLE;         // M_*TRIPLE
    float* absig   = qkv_c   + (size_t)M_ * TRIPLE;         // M_*32
    float* gpre    = absig   + (size_t)M_ * 32;             // M_*INNER
    float* og      = qkv_pre;                               // alias

    dim3 blk(256);
    gemm_bt_f32<<<dim3(TRIPLE / 64, M_ / 64), blk, 0, stream>>>(x, W_qkv, nullptr, qkv_pre, M_, TRIPLE, DM, 0);
    gemm_bt_f32<<<dim3(1, M_ / 64), blk, 0, stream>>>(x, W_ab, b_ab, absig, M_, 32, DM, 2);
    gemm_bt_f32<<<dim3(INNER / 64, M_ / 64), blk, 0, stream>>>(x, W_g, nullptr, gpre, M_, INNER, DM, 1);
    conv_silu_norm<<<dim3(B_ * N_), blk, 0, stream>>>(qkv_pre, conv_w, qkv_c);
    recurrence<<<dim3(512), blk, 0, stream>>>(qkv_c, absig, gpre, og);
    gemm_bt_f32<<<dim3(INNER / 64, M_ / 64), blk, 0, stream>>>(og, W_o, nullptr, out, M_, INNER, DM, 0);
}

// Round 4
// 4355.270 us; speedup vs baseline: 1.4920x; 1.1466x over previous
//
#include <hip/hip_runtime.h>
#include <math.h>
#include <stddef.h>

#define B_ 2
#define N_ 2048
#define DM 2048
#define H_ 16
#define HD 128
#define INNER 2048
#define TRIPLE 6144
#define M_ (B_ * N_)   // 4096
#define CH 8           // tokens per register chunk in recurrence
#define NC (N_ / CH)   // 256 chunks

__device__ __forceinline__ float sig_(float x) { return 1.0f / (1.0f + __expf(-x)); }

// C[m,n] = sum_k A[m,k] * W[n,k]  (+bias, +activation)
// act: 0 = none, 1 = silu, 2 = sigmoid
__global__ __launch_bounds__(256) void gemm_bt_f32(
    const float* __restrict__ A, const float* __restrict__ W,
    const float* __restrict__ bias, float* __restrict__ C,
    int M, int Nn, int K, int act)
{
    __shared__ float As[16][72];
    __shared__ float Bs[16][72];
    const int tid = threadIdx.x;
    const int tx = tid & 15, ty = tid >> 4;
    const int col0 = blockIdx.x * 64;
    const int row0 = blockIdx.y * 64;
    const int lr = tid >> 2;
    const int lk = (tid & 3) * 4;

    float acc[4][4];
#pragma unroll
    for (int i = 0; i < 4; ++i)
#pragma unroll
        for (int j = 0; j < 4; ++j) acc[i][j] = 0.f;

    const float* Arow = A + (size_t)(row0 + lr) * K;
    const float* Wrow = W + (size_t)(col0 + lr) * K;
    const bool wvalid = (col0 + lr) < Nn;

    for (int k0 = 0; k0 < K; k0 += 16) {
        float4 a4 = *(const float4*)(Arow + k0 + lk);
        float4 b4 = wvalid ? *(const float4*)(Wrow + k0 + lk) : make_float4(0.f, 0.f, 0.f, 0.f);
        __syncthreads();
        As[lk + 0][lr] = a4.x; As[lk + 1][lr] = a4.y; As[lk + 2][lr] = a4.z; As[lk + 3][lr] = a4.w;
        Bs[lk + 0][lr] = b4.x; Bs[lk + 1][lr] = b4.y; Bs[lk + 2][lr] = b4.z; Bs[lk + 3][lr] = b4.w;
        __syncthreads();
#pragma unroll
        for (int kk = 0; kk < 16; ++kk) {
            float4 av = *(const float4*)&As[kk][ty * 4];
            float4 bv = *(const float4*)&Bs[kk][tx * 4];
            acc[0][0] += av.x * bv.x; acc[0][1] += av.x * bv.y; acc[0][2] += av.x * bv.z; acc[0][3] += av.x * bv.w;
            acc[1][0] += av.y * bv.x; acc[1][1] += av.y * bv.y; acc[1][2] += av.y * bv.z; acc[1][3] += av.y * bv.w;
            acc[2][0] += av.z * bv.x; acc[2][1] += av.z * bv.y; acc[2][2] += av.z * bv.z; acc[2][3] += av.z * bv.w;
            acc[3][0] += av.w * bv.x; acc[3][1] += av.w * bv.y; acc[3][2] += av.w * bv.z; acc[3][3] += av.w * bv.w;
        }
    }

#pragma unroll
    for (int i = 0; i < 4; ++i) {
        int r = row0 + ty * 4 + i;
#pragma unroll
        for (int j = 0; j < 4; ++j) {
            int c = col0 + tx * 4 + j;
            if (c < Nn) {
                float v = acc[i][j];
                if (bias) v += bias[c];
                if (act == 1) v = v * sig_(v);
                else if (act == 2) v = sig_(v);
                C[(size_t)r * Nn + c] = v;
            }
        }
    }
}

__global__ __launch_bounds__(256) void conv_silu_norm(
    const float* __restrict__ qkv, const float* __restrict__ conv_w,
    float* __restrict__ outb)
{
    __shared__ float buf[TRIPLE];
    __shared__ float scales[32];
    const int bn = blockIdx.x;
    const int n = bn & (N_ - 1);
    const int tid = threadIdx.x;
    const float* base = qkv + (size_t)bn * TRIPLE;

    for (int c = tid; c < TRIPLE; c += 256) {
        float acc = 0.f;
#pragma unroll
        for (int j = 0; j < 4; ++j) {
            int nn = n - 3 + j;
            float xv = (nn >= 0) ? base[(ptrdiff_t)(j - 3) * TRIPLE + c] : 0.f;
            acc += xv * conv_w[c * 4 + j];
        }
        buf[c] = acc * sig_(acc);
    }
    __syncthreads();

    const int g = tid >> 3, l = tid & 7;
    {
        int off = (g < 16) ? g * HD : 2048 + (g - 16) * HD;
        float s = 0.f;
        for (int i = l; i < HD; i += 8) { float v = buf[off + i]; s += v * v; }
        s += __shfl_xor(s, 1); s += __shfl_xor(s, 2); s += __shfl_xor(s, 4);
        if (l == 0) scales[g] = 1.0f / fmaxf(sqrtf(s), 1e-12f);
    }
    __syncthreads();

    float* ob = outb + (size_t)bn * TRIPLE;
    for (int c = tid; c < TRIPLE; c += 256) {
        float sc = 1.f;
        if (c < 2048) sc = scales[c >> 7];
        else if (c < 4096) sc = scales[16 + ((c - 2048) >> 7)];
        ob[c] = buf[c] * sc;
    }
}

// Delta-rule recurrence, barrier-free + token-chunked (CH=8) register
// double-buffer. Each 32-lane half-wave owns one state row (4 floats/lane).
// Block mapping: bh = blk&31, rblk = blk>>5 -> all 16 blocks of one (b,h)
// share blk%8 (same XCD) so its L2 fetches the k/q/v stream once.
__global__ __launch_bounds__(256) void recurrence(
    const float* __restrict__ qkvc, const float* __restrict__ absig,
    const float* __restrict__ gpre, float* __restrict__ og)
{
    const int blk  = blockIdx.x;          // 0..511
    const int bh   = blk & 31;
    const int b    = bh >> 4;
    const int h    = bh & (H_ - 1);
    const int rblk = blk >> 5;            // 0..15
    const int tid  = threadIdx.x;
    const int wave = tid >> 6;
    const int lane = tid & 63;
    const int half = lane >> 5;
    const int lc   = lane & 31;
    const int row  = rblk * 8 + wave * 2 + half;   // 0..127
    const int c    = lc * 4;

    const size_t tokbase = (size_t)b * N_ * TRIPLE;
    const float* qbase = qkvc + tokbase + h * HD;
    const float* kbase = qkvc + tokbase + 2048 + h * HD;
    const float* vbase = qkvc + tokbase + 4096 + h * HD;
    const float* abb   = absig + (size_t)b * N_ * 32;
    const float* gb    = gpre + (size_t)b * N_ * INNER + h * HD + row;
    float*       ob    = og   + (size_t)b * N_ * INNER + h * HD + row;

    float4 s = make_float4(0.f, 0.f, 0.f, 0.f);

    float4 kc[CH], qc[CH]; float vc[CH], ac[CH], bc[CH];
#pragma unroll
    for (int t = 0; t < CH; ++t) {
        size_t o_ = (size_t)t * TRIPLE;
        kc[t] = *(const float4*)(kbase + o_ + c);
        qc[t] = *(const float4*)(qbase + o_ + c);
        vc[t] = vbase[o_ + row];
        ac[t] = abb[t * 32 + h];
        bc[t] = abb[t * 32 + 16 + h];
    }

    for (int ch = 0; ch < NC; ++ch) {
        // prefetch next chunk into a second register set
        const int np = (ch + 1 < NC) ? ch + 1 : ch;
        const size_t nb = (size_t)np * CH * TRIPLE;
        float4 kn[CH], qn[CH]; float vn[CH], an[CH], bn[CH];
#pragma unroll
        for (int t = 0; t < CH; ++t) {
            size_t o_ = nb + (size_t)t * TRIPLE;
            kn[t] = *(const float4*)(kbase + o_ + c);
            qn[t] = *(const float4*)(qbase + o_ + c);
            vn[t] = vbase[o_ + row];
            an[t] = abb[(np * CH + t) * 32 + h];
            bn[t] = abb[(np * CH + t) * 32 + 16 + h];
        }

#pragma unroll
        for (int t = 0; t < CH; ++t) {
            const float a = ac[t], bt = bc[t];
            float dot = s.x * kc[t].x + s.y * kc[t].y + s.z * kc[t].z + s.w * kc[t].w;
            dot += __shfl_xor(dot, 1);  dot += __shfl_xor(dot, 2);
            dot += __shfl_xor(dot, 4);  dot += __shfl_xor(dot, 8);
            dot += __shfl_xor(dot, 16);

            const float u = bt * (vc[t] - a * dot);
            s.x = a * s.x + u * kc[t].x;
            s.y = a * s.y + u * kc[t].y;
            s.z = a * s.z + u * kc[t].z;
            s.w = a * s.w + u * kc[t].w;

            float od = s.x * qc[t].x + s.y * qc[t].y + s.z * qc[t].z + s.w * qc[t].w;
            od += __shfl_xor(od, 1);  od += __shfl_xor(od, 2);
            od += __shfl_xor(od, 4);  od += __shfl_xor(od, 8);
            od += __shfl_xor(od, 16);

            if (lc == 0) {
                size_t idx = (size_t)(ch * CH + t) * INNER;
                ob[idx] = od * gb[idx];
            }
        }

#pragma unroll
        for (int t = 0; t < CH; ++t) {
            kc[t] = kn[t]; qc[t] = qn[t]; vc[t] = vn[t]; ac[t] = an[t]; bc[t] = bn[t];
        }
    }
}

extern "C" void kernel_launch(void* const* d_in, const int* in_sizes, int n_in,
                              void* d_out, int out_size, void* d_ws, size_t ws_size,
                              hipStream_t stream) {
    const float* x      = (const float*)d_in[0];
    const float* W_qkv  = (const float*)d_in[1];
    const float* conv_w = (const float*)d_in[2];
    const float* W_ab   = (const float*)d_in[3];
    const float* b_ab   = (const float*)d_in[4];
    const float* W_g    = (const float*)d_in[5];
    const float* W_o    = (const float*)d_in[6];
    float* out = (float*)d_out;

    // ws: og aliases qkv_pre (dead after conv_silu_norm; stream serializes).
    float* qkv_pre = (float*)d_ws;                          // M_*TRIPLE
    float* qkv_c   = qkv_pre + (size_t)M_ * TRIPLE;         // M_*TRIPLE
    float* absig   = qkv_c   + (size_t)M_ * TRIPLE;         // M_*32
    float* gpre    = absig   + (size_t)M_ * 32;             // M_*INNER
    float* og      = qkv_pre;                               // alias

    dim3 blk(256);
    gemm_bt_f32<<<dim3(TRIPLE / 64, M_ / 64), blk, 0, stream>>>(x, W_qkv, nullptr, qkv_pre, M_, TRIPLE, DM, 0);
    gemm_bt_f32<<<dim3(1, M_ / 64), blk, 0, stream>>>(x, W_ab, b_ab, absig, M_, 32, DM, 2);
    gemm_bt_f32<<<dim3(INNER / 64, M_ / 64), blk, 0, stream>>>(x, W_g, nullptr, gpre, M_, INNER, DM, 1);
    conv_silu_norm<<<dim3(B_ * N_), blk, 0, stream>>>(qkv_pre, conv_w, qkv_c);
    recurrence<<<dim3(512), blk, 0, stream>>>(qkv_c, absig, gpre, og);
    gemm_bt_f32<<<dim3(INNER / 64, M_ / 64), blk, 0, stream>>>(og, W_o, nullptr, out, M_, INNER, DM, 0);
}

// Round 5
// 3444.440 us; speedup vs baseline: 1.8865x; 1.2644x over previous
//
#include <hip/hip_runtime.h>
#include <math.h>
#include <stddef.h>

#define B_ 2
#define N_ 2048
#define DM 2048
#define H_ 16
#define HD 128
#define INNER 2048
#define TRIPLE 6144
#define M_ (B_ * N_)   // 4096
#define RCH 4          // tokens per register chunk in recurrence
#define NCH (N_ / RCH)

__device__ __forceinline__ float sig_(float x) { return 1.0f / (1.0f + __expf(-x)); }

// DPP 16-lane sum: quad xor1, quad xor2, half-row mirror, row mirror.
// All VALU latency — no LDS crossbar. Result in ALL 16 lanes of the row.
template <int CTRL>
__device__ __forceinline__ float dpp_add_(float x) {
    return x + __int_as_float(__builtin_amdgcn_update_dpp(
        0, __float_as_int(x), CTRL, 0xF, 0xF, true));
}
__device__ __forceinline__ float dpp_sum16(float x) {
    x = dpp_add_<0xB1>(x);    // quad_perm [1,0,3,2]  (xor 1)
    x = dpp_add_<0x4E>(x);    // quad_perm [2,3,0,1]  (xor 2)
    x = dpp_add_<0x141>(x);   // row_half_mirror      (xor 4 within 8)
    x = dpp_add_<0x140>(x);   // row_mirror           (xor 8 within 16)
    return x;
}

// C[m,n] = sum_k A[m,k] * W[n,k]  (+bias, +activation)
__global__ __launch_bounds__(256) void gemm_bt_f32(
    const float* __restrict__ A, const float* __restrict__ W,
    const float* __restrict__ bias, float* __restrict__ C,
    int M, int Nn, int K, int act)
{
    __shared__ float As[16][72];
    __shared__ float Bs[16][72];
    const int tid = threadIdx.x;
    const int tx = tid & 15, ty = tid >> 4;
    const int col0 = blockIdx.x * 64;
    const int row0 = blockIdx.y * 64;
    const int lr = tid >> 2;
    const int lk = (tid & 3) * 4;

    float acc[4][4];
#pragma unroll
    for (int i = 0; i < 4; ++i)
#pragma unroll
        for (int j = 0; j < 4; ++j) acc[i][j] = 0.f;

    const float* Arow = A + (size_t)(row0 + lr) * K;
    const float* Wrow = W + (size_t)(col0 + lr) * K;
    const bool wvalid = (col0 + lr) < Nn;

    for (int k0 = 0; k0 < K; k0 += 16) {
        float4 a4 = *(const float4*)(Arow + k0 + lk);
        float4 b4 = wvalid ? *(const float4*)(Wrow + k0 + lk) : make_float4(0.f, 0.f, 0.f, 0.f);
        __syncthreads();
        As[lk + 0][lr] = a4.x; As[lk + 1][lr] = a4.y; As[lk + 2][lr] = a4.z; As[lk + 3][lr] = a4.w;
        Bs[lk + 0][lr] = b4.x; Bs[lk + 1][lr] = b4.y; Bs[lk + 2][lr] = b4.z; Bs[lk + 3][lr] = b4.w;
        __syncthreads();
#pragma unroll
        for (int kk = 0; kk < 16; ++kk) {
            float4 av = *(const float4*)&As[kk][ty * 4];
            float4 bv = *(const float4*)&Bs[kk][tx * 4];
            acc[0][0] += av.x * bv.x; acc[0][1] += av.x * bv.y; acc[0][2] += av.x * bv.z; acc[0][3] += av.x * bv.w;
            acc[1][0] += av.y * bv.x; acc[1][1] += av.y * bv.y; acc[1][2] += av.y * bv.z; acc[1][3] += av.y * bv.w;
            acc[2][0] += av.z * bv.x; acc[2][1] += av.z * bv.y; acc[2][2] += av.z * bv.z; acc[2][3] += av.z * bv.w;
            acc[3][0] += av.w * bv.x; acc[3][1] += av.w * bv.y; acc[3][2] += av.w * bv.z; acc[3][3] += av.w * bv.w;
        }
    }

#pragma unroll
    for (int i = 0; i < 4; ++i) {
        int r = row0 + ty * 4 + i;
#pragma unroll
        for (int j = 0; j < 4; ++j) {
            int c = col0 + tx * 4 + j;
            if (c < Nn) {
                float v = acc[i][j];
                if (bias) v += bias[c];
                if (act == 1) v = v * sig_(v);
                else if (act == 2) v = sig_(v);
                C[(size_t)r * Nn + c] = v;
            }
        }
    }
}

__global__ __launch_bounds__(256) void conv_silu_norm(
    const float* __restrict__ qkv, const float* __restrict__ conv_w,
    float* __restrict__ outb)
{
    __shared__ float buf[TRIPLE];
    __shared__ float scales[32];
    const int bn = blockIdx.x;
    const int n = bn & (N_ - 1);
    const int tid = threadIdx.x;
    const float* base = qkv + (size_t)bn * TRIPLE;

    for (int c = tid; c < TRIPLE; c += 256) {
        float acc = 0.f;
#pragma unroll
        for (int j = 0; j < 4; ++j) {
            int nn = n - 3 + j;
            float xv = (nn >= 0) ? base[(ptrdiff_t)(j - 3) * TRIPLE + c] : 0.f;
            acc += xv * conv_w[c * 4 + j];
        }
        buf[c] = acc * sig_(acc);
    }
    __syncthreads();

    const int g = tid >> 3, l = tid & 7;
    {
        int off = (g < 16) ? g * HD : 2048 + (g - 16) * HD;
        float s = 0.f;
        for (int i = l; i < HD; i += 8) { float v = buf[off + i]; s += v * v; }
        s += __shfl_xor(s, 1); s += __shfl_xor(s, 2); s += __shfl_xor(s, 4);
        if (l == 0) scales[g] = 1.0f / fmaxf(sqrtf(s), 1e-12f);
    }
    __syncthreads();

    float* ob = outb + (size_t)bn * TRIPLE;
    for (int c = tid; c < TRIPLE; c += 256) {
        float sc = 1.f;
        if (c < 2048) sc = scales[c >> 7];
        else if (c < 4096) sc = scales[16 + ((c - 2048) >> 7)];
        ob[c] = buf[c] * sc;
    }
}

// Delta-rule recurrence: 16 lanes/row, 8 cols/lane, DPP reductions (no LDS,
// no barriers, no ds_swizzle on the critical path). Wave = 4 rows.
// Grid 256 blocks: bh = blk&31 (same-XCD clustering), rblk = blk>>5 (0..7).
// CH=4 token register double-buffer; od reductions deferred to chunk end.
__global__ __launch_bounds__(256) void recurrence(
    const float* __restrict__ qkvc, const float* __restrict__ absig,
    const float* __restrict__ gpre, float* __restrict__ og)
{
    const int blk  = blockIdx.x;          // 0..255
    const int bh   = blk & 31;
    const int b    = bh >> 4;
    const int h    = bh & (H_ - 1);
    const int rblk = blk >> 5;            // 0..7
    const int tid  = threadIdx.x;
    const int wave = tid >> 6;
    const int lane = tid & 63;
    const int grp  = lane >> 4;           // row within wave (0..3)
    const int lc   = lane & 15;           // col chunk within row
    const int row  = rblk * 16 + wave * 4 + grp;   // 0..127
    const int c0   = lc * 8;

    const size_t tokbase = (size_t)b * N_ * TRIPLE;
    const float* qbase = qkvc + tokbase + h * HD + c0;
    const float* kbase = qkvc + tokbase + 2048 + h * HD + c0;
    const float* vbase = qkvc + tokbase + 4096 + h * HD + row;
    const float* abb   = absig + (size_t)b * N_ * 32;
    const float* gb    = gpre + (size_t)b * N_ * INNER + h * HD + row;
    float*       ob    = og   + (size_t)b * N_ * INNER + h * HD + row;

    float4 s0 = make_float4(0.f, 0.f, 0.f, 0.f);
    float4 s1 = make_float4(0.f, 0.f, 0.f, 0.f);

    float4 kc0[RCH], kc1[RCH], qc0[RCH], qc1[RCH];
    float vc[RCH], ac[RCH], bc[RCH];
#pragma unroll
    for (int t = 0; t < RCH; ++t) {
        size_t o_ = (size_t)t * TRIPLE;
        kc0[t] = *(const float4*)(kbase + o_);
        kc1[t] = *(const float4*)(kbase + o_ + 4);
        qc0[t] = *(const float4*)(qbase + o_);
        qc1[t] = *(const float4*)(qbase + o_ + 4);
        vc[t]  = vbase[o_];
        ac[t]  = abb[t * 32 + h];
        bc[t]  = abb[t * 32 + 16 + h];
    }

    for (int ch = 0; ch < NCH; ++ch) {
        const int np = (ch + 1 < NCH) ? ch + 1 : ch;
        float4 kn0[RCH], kn1[RCH], qn0[RCH], qn1[RCH];
        float vn[RCH], an[RCH], bn[RCH];
#pragma unroll
        for (int t = 0; t < RCH; ++t) {
            size_t o_ = (size_t)(np * RCH + t) * TRIPLE;
            kn0[t] = *(const float4*)(kbase + o_);
            kn1[t] = *(const float4*)(kbase + o_ + 4);
            qn0[t] = *(const float4*)(qbase + o_);
            qn1[t] = *(const float4*)(qbase + o_ + 4);
            vn[t]  = vbase[o_];
            an[t]  = abb[(np * RCH + t) * 32 + h];
            bn[t]  = abb[(np * RCH + t) * 32 + 16 + h];
        }

        float odp[RCH];
#pragma unroll
        for (int t = 0; t < RCH; ++t) {
            const float a = ac[t], bt = bc[t];
            // dot = S_row . k  (tree over 8 regs, then 16-lane DPP sum)
            float d0 = s0.x * kc0[t].x + s0.y * kc0[t].y;
            float d1 = s0.z * kc0[t].z + s0.w * kc0[t].w;
            float d2 = s1.x * kc1[t].x + s1.y * kc1[t].y;
            float d3 = s1.z * kc1[t].z + s1.w * kc1[t].w;
            float dot = dpp_sum16((d0 + d1) + (d2 + d3));

            const float u = bt * (vc[t] - a * dot);
            s0.x = a * s0.x + u * kc0[t].x;
            s0.y = a * s0.y + u * kc0[t].y;
            s0.z = a * s0.z + u * kc0[t].z;
            s0.w = a * s0.w + u * kc0[t].w;
            s1.x = a * s1.x + u * kc1[t].x;
            s1.y = a * s1.y + u * kc1[t].y;
            s1.z = a * s1.z + u * kc1[t].z;
            s1.w = a * s1.w + u * kc1[t].w;

            // od partial (reduction deferred to chunk end)
            float e0 = s0.x * qc0[t].x + s0.y * qc0[t].y;
            float e1 = s0.z * qc0[t].z + s0.w * qc0[t].w;
            float e2 = s1.x * qc1[t].x + s1.y * qc1[t].y;
            float e3 = s1.z * qc1[t].z + s1.w * qc1[t].w;
            odp[t] = (e0 + e1) + (e2 + e3);
        }

        // deferred, mutually independent DPP reductions (latency interleaved)
        float od[RCH];
#pragma unroll
        for (int t = 0; t < RCH; ++t) od[t] = dpp_sum16(odp[t]);

        if (lc == 0) {
#pragma unroll
            for (int t = 0; t < RCH; ++t) {
                size_t idx = (size_t)(ch * RCH + t) * INNER;
                ob[idx] = od[t] * gb[idx];
            }
        }

#pragma unroll
        for (int t = 0; t < RCH; ++t) {
            kc0[t] = kn0[t]; kc1[t] = kn1[t];
            qc0[t] = qn0[t]; qc1[t] = qn1[t];
            vc[t] = vn[t]; ac[t] = an[t]; bc[t] = bn[t];
        }
    }
}

extern "C" void kernel_launch(void* const* d_in, const int* in_sizes, int n_in,
                              void* d_out, int out_size, void* d_ws, size_t ws_size,
                              hipStream_t stream) {
    const float* x      = (const float*)d_in[0];
    const float* W_qkv  = (const float*)d_in[1];
    const float* conv_w = (const float*)d_in[2];
    const float* W_ab   = (const float*)d_in[3];
    const float* b_ab   = (const float*)d_in[4];
    const float* W_g    = (const float*)d_in[5];
    const float* W_o    = (const float*)d_in[6];
    float* out = (float*)d_out;

    // ws: og aliases qkv_pre (dead after conv_silu_norm; stream serializes).
    float* qkv_pre = (float*)d_ws;                          // M_*TRIPLE
    float* qkv_c   = qkv_pre + (size_t)M_ * TRIPLE;         // M_*TRIPLE
    float* absig   = qkv_c   + (size_t)M_ * TRIPLE;         // M_*32
    float* gpre    = absig   + (size_t)M_ * 32;             // M_*INNER
    float* og      = qkv_pre;                               // alias

    dim3 blk(256);
    gemm_bt_f32<<<dim3(TRIPLE / 64, M_ / 64), blk, 0, stream>>>(x, W_qkv, nullptr, qkv_pre, M_, TRIPLE, DM, 0);
    gemm_bt_f32<<<dim3(1, M_ / 64), blk, 0, stream>>>(x, W_ab, b_ab, absig, M_, 32, DM, 2);
    gemm_bt_f32<<<dim3(INNER / 64, M_ / 64), blk, 0, stream>>>(x, W_g, nullptr, gpre, M_, INNER, DM, 1);
    conv_silu_norm<<<dim3(B_ * N_), blk, 0, stream>>>(qkv_pre, conv_w, qkv_c);
    recurrence<<<dim3(256), blk, 0, stream>>>(qkv_c, absig, gpre, og);
    gemm_bt_f32<<<dim3(INNER / 64, M_ / 64), blk, 0, stream>>>(og, W_o, nullptr, out, M_, INNER, DM, 0);
}

// Round 6
// 1169.485 us; speedup vs baseline: 5.5562x; 2.9453x over previous
//
#include <hip/hip_runtime.h>
#include <math.h>
#include <stddef.h>

#define B_ 2
#define N_ 2048
#define DM 2048
#define H_ 16
#define HD 128
#define INNER 2048
#define TRIPLE 6144
#define M_ (B_ * N_)   // 4096
#define RCH 4          // tokens per register chunk in recurrence
#define NCH (N_ / RCH)

typedef __bf16 bf16x8 __attribute__((ext_vector_type(8)));
typedef float  f32x4v __attribute__((ext_vector_type(4)));
typedef __attribute__((address_space(1))) const void gvoid;
typedef __attribute__((address_space(3))) void lvoid;

__device__ __forceinline__ float sig_(float x) { return 1.0f / (1.0f + __expf(-x)); }

__device__ __forceinline__ unsigned short f2bf(float f) {
    unsigned u = __float_as_uint(f);
    u += 0x7FFFu + ((u >> 16) & 1u);     // RNE
    return (unsigned short)(u >> 16);
}
__device__ __forceinline__ float bf2f(unsigned short h) {
    return __uint_as_float((unsigned)h << 16);
}
__device__ __forceinline__ void unpack8(uint4 r, float* f) {
    f[0] = __uint_as_float(r.x << 16); f[1] = __uint_as_float(r.x & 0xffff0000u);
    f[2] = __uint_as_float(r.y << 16); f[3] = __uint_as_float(r.y & 0xffff0000u);
    f[4] = __uint_as_float(r.z << 16); f[5] = __uint_as_float(r.z & 0xffff0000u);
    f[6] = __uint_as_float(r.w << 16); f[7] = __uint_as_float(r.w & 0xffff0000u);
}

// DPP 16-lane sum (VALU-only, no LDS crossbar).
template <int CTRL>
__device__ __forceinline__ float dpp_add_(float x) {
    return x + __int_as_float(__builtin_amdgcn_update_dpp(
        0, __float_as_int(x), CTRL, 0xF, 0xF, true));
}
__device__ __forceinline__ float dpp_sum16(float x) {
    x = dpp_add_<0xB1>(x);    // quad_perm xor1
    x = dpp_add_<0x4E>(x);    // quad_perm xor2
    x = dpp_add_<0x141>(x);   // row_half_mirror
    x = dpp_add_<0x140>(x);   // row_mirror
    return x;
}

__global__ __launch_bounds__(256) void cast_bf16(
    const float* __restrict__ in, unsigned short* __restrict__ out, int n)
{
    int i = (blockIdx.x * 256 + threadIdx.x) * 4;
    if (i < n) {
        float4 v = *(const float4*)(in + i);
        out[i + 0] = f2bf(v.x); out[i + 1] = f2bf(v.y);
        out[i + 2] = f2bf(v.z); out[i + 3] = f2bf(v.w);
    }
}

// bf16 MFMA GEMM: C[m,n] = A[m,k] * Bw[n,k]  (both row-major bf16, B^T form).
// 128x128 tile, BK=32, 4 waves in 2x2, 16x16x32 MFMA, global_load_lds(16B).
// ACT: 0 none, 1 silu. OUT_BF16: write bf16 instead of f32.
template <int ACT, int OUT_BF16>
__global__ __launch_bounds__(256) void gemm_bf16(
    const unsigned short* __restrict__ A, const unsigned short* __restrict__ Bw,
    void* __restrict__ C, int M, int N, int K)
{
    __shared__ unsigned short As[128 * 32];   // row*32 + k, no pad (lds-dma order)
    __shared__ unsigned short Bs[128 * 32];
    const int tid  = threadIdx.x;
    const int w    = tid >> 6;
    const int l    = tid & 63;
    const int row0 = blockIdx.y * 128;
    const int col0 = blockIdx.x * 128;

    // staging: thread t -> 16B at row (t>>2), k-group (t&3)*8; two halves (rows +0,+64)
    const int sr = tid >> 2;
    const int sc = (tid & 3) * 8;
    const unsigned short* Ag0 = A  + (size_t)(row0 + sr) * K + sc;
    const unsigned short* Ag1 = A  + (size_t)(row0 + 64 + sr) * K + sc;
    const unsigned short* Bg0 = Bw + (size_t)(col0 + sr) * K + sc;
    const unsigned short* Bg1 = Bw + (size_t)(col0 + 64 + sr) * K + sc;
    unsigned short* AsW0 = As + w * 512;            // wave-uniform bases
    unsigned short* AsW1 = As + 2048 + w * 512;
    unsigned short* BsW0 = Bs + w * 512;
    unsigned short* BsW1 = Bs + 2048 + w * 512;

    f32x4v acc[4][4];
#pragma unroll
    for (int i = 0; i < 4; ++i)
#pragma unroll
        for (int j = 0; j < 4; ++j) acc[i][j] = (f32x4v){0.f, 0.f, 0.f, 0.f};

    const int m0 = (w >> 1) * 64;
    const int n0 = (w & 1) * 64;
    const int lr = l & 15;
    const int lk = (l >> 4) * 8;

    for (int k0 = 0; k0 < K; k0 += 32) {
        __syncthreads();
        __builtin_amdgcn_global_load_lds((gvoid*)(Ag0 + k0), (lvoid*)AsW0, 16, 0, 0);
        __builtin_amdgcn_global_load_lds((gvoid*)(Ag1 + k0), (lvoid*)AsW1, 16, 0, 0);
        __builtin_amdgcn_global_load_lds((gvoid*)(Bg0 + k0), (lvoid*)BsW0, 16, 0, 0);
        __builtin_amdgcn_global_load_lds((gvoid*)(Bg1 + k0), (lvoid*)BsW1, 16, 0, 0);
        __syncthreads();

        bf16x8 af[4], bfr[4];
#pragma unroll
        for (int i = 0; i < 4; ++i) {
            af[i]  = *(const bf16x8*)&As[(m0 + i * 16 + lr) * 32 + lk];
            bfr[i] = *(const bf16x8*)&Bs[(n0 + i * 16 + lr) * 32 + lk];
        }
#pragma unroll
        for (int mi = 0; mi < 4; ++mi)
#pragma unroll
            for (int ni = 0; ni < 4; ++ni)
                acc[mi][ni] = __builtin_amdgcn_mfma_f32_16x16x32_bf16(
                    af[mi], bfr[ni], acc[mi][ni], 0, 0, 0);
    }

    // C/D layout: col = lane&15, row = (lane>>4)*4 + reg
#pragma unroll
    for (int mi = 0; mi < 4; ++mi) {
#pragma unroll
        for (int j = 0; j < 4; ++j) {
            int r = row0 + m0 + mi * 16 + (l >> 4) * 4 + j;
#pragma unroll
            for (int ni = 0; ni < 4; ++ni) {
                int c = col0 + n0 + ni * 16 + lr;
                float v = acc[mi][ni][j];
                if (ACT == 1) v = v * sig_(v);
                if (OUT_BF16) ((unsigned short*)C)[(size_t)r * N + c] = f2bf(v);
                else          ((float*)C)[(size_t)r * N + c] = v;
            }
        }
    }
}

// fp32 fallback GEMM (used only for the tiny ab projection, N=32)
__global__ __launch_bounds__(256) void gemm_bt_f32(
    const float* __restrict__ A, const float* __restrict__ W,
    const float* __restrict__ bias, float* __restrict__ C,
    int M, int Nn, int K, int act)
{
    __shared__ float As[16][72];
    __shared__ float Bs[16][72];
    const int tid = threadIdx.x;
    const int tx = tid & 15, ty = tid >> 4;
    const int col0 = blockIdx.x * 64;
    const int row0 = blockIdx.y * 64;
    const int lr = tid >> 2;
    const int lk = (tid & 3) * 4;

    float acc[4][4];
#pragma unroll
    for (int i = 0; i < 4; ++i)
#pragma unroll
        for (int j = 0; j < 4; ++j) acc[i][j] = 0.f;

    const float* Arow = A + (size_t)(row0 + lr) * K;
    const float* Wrow = W + (size_t)(col0 + lr) * K;
    const bool wvalid = (col0 + lr) < Nn;

    for (int k0 = 0; k0 < K; k0 += 16) {
        float4 a4 = *(const float4*)(Arow + k0 + lk);
        float4 b4 = wvalid ? *(const float4*)(Wrow + k0 + lk) : make_float4(0.f, 0.f, 0.f, 0.f);
        __syncthreads();
        As[lk + 0][lr] = a4.x; As[lk + 1][lr] = a4.y; As[lk + 2][lr] = a4.z; As[lk + 3][lr] = a4.w;
        Bs[lk + 0][lr] = b4.x; Bs[lk + 1][lr] = b4.y; Bs[lk + 2][lr] = b4.z; Bs[lk + 3][lr] = b4.w;
        __syncthreads();
#pragma unroll
        for (int kk = 0; kk < 16; ++kk) {
            float4 av = *(const float4*)&As[kk][ty * 4];
            float4 bv = *(const float4*)&Bs[kk][tx * 4];
            acc[0][0] += av.x * bv.x; acc[0][1] += av.x * bv.y; acc[0][2] += av.x * bv.z; acc[0][3] += av.x * bv.w;
            acc[1][0] += av.y * bv.x; acc[1][1] += av.y * bv.y; acc[1][2] += av.y * bv.z; acc[1][3] += av.y * bv.w;
            acc[2][0] += av.z * bv.x; acc[2][1] += av.z * bv.y; acc[2][2] += av.z * bv.z; acc[2][3] += av.z * bv.w;
            acc[3][0] += av.w * bv.x; acc[3][1] += av.w * bv.y; acc[3][2] += av.w * bv.z; acc[3][3] += av.w * bv.w;
        }
    }

#pragma unroll
    for (int i = 0; i < 4; ++i) {
        int r = row0 + ty * 4 + i;
#pragma unroll
        for (int j = 0; j < 4; ++j) {
            int c = col0 + tx * 4 + j;
            if (c < Nn) {
                float v = acc[i][j];
                if (bias) v += bias[c];
                if (act == 1) v = v * sig_(v);
                else if (act == 2) v = sig_(v);
                C[(size_t)r * Nn + c] = v;
            }
        }
    }
}

// conv(K=4, causal, depthwise) + silu + per-head l2norm of q,k. bf16 in/out.
__global__ __launch_bounds__(256) void conv_silu_norm(
    const unsigned short* __restrict__ qkv, const float* __restrict__ conv_w,
    unsigned short* __restrict__ outb)
{
    __shared__ float buf[TRIPLE];
    __shared__ float scales[32];
    const int bn = blockIdx.x;
    const int n = bn & (N_ - 1);
    const int tid = threadIdx.x;
    const unsigned short* base = qkv + (size_t)bn * TRIPLE;

    for (int c = tid; c < TRIPLE; c += 256) {
        float acc = 0.f;
#pragma unroll
        for (int j = 0; j < 4; ++j) {
            int nn = n - 3 + j;
            float xv = (nn >= 0) ? bf2f(base[(ptrdiff_t)(j - 3) * TRIPLE + c]) : 0.f;
            acc += xv * conv_w[c * 4 + j];
        }
        buf[c] = acc * sig_(acc);
    }
    __syncthreads();

    const int g = tid >> 3, l = tid & 7;
    {
        int off = (g < 16) ? g * HD : 2048 + (g - 16) * HD;
        float s = 0.f;
        for (int i = l; i < HD; i += 8) { float v = buf[off + i]; s += v * v; }
        s += __shfl_xor(s, 1); s += __shfl_xor(s, 2); s += __shfl_xor(s, 4);
        if (l == 0) scales[g] = 1.0f / fmaxf(sqrtf(s), 1e-12f);
    }
    __syncthreads();

    unsigned short* ob = outb + (size_t)bn * TRIPLE;
    for (int c = tid; c < TRIPLE; c += 256) {
        float sc = 1.f;
        if (c < 2048) sc = scales[c >> 7];
        else if (c < 4096) sc = scales[16 + ((c - 2048) >> 7)];
        ob[c] = f2bf(buf[c] * sc);
    }
}

// Delta-rule recurrence (fp32 math, bf16 loads/stores). 16 lanes/row, 8 cols/lane,
// DPP reductions, CH=4 register double-buffer, same-XCD block clustering.
__global__ __launch_bounds__(256) void recurrence(
    const unsigned short* __restrict__ qkvc, const float* __restrict__ absig,
    const float* __restrict__ gpre, unsigned short* __restrict__ og)
{
    const int blk  = blockIdx.x;          // 0..255
    const int bh   = blk & 31;
    const int b    = bh >> 4;
    const int h    = bh & (H_ - 1);
    const int rblk = blk >> 5;            // 0..7
    const int tid  = threadIdx.x;
    const int wave = tid >> 6;
    const int lane = tid & 63;
    const int grp  = lane >> 4;
    const int lc   = lane & 15;
    const int row  = rblk * 16 + wave * 4 + grp;   // 0..127
    const int c0   = lc * 8;

    const size_t tokbase = (size_t)b * N_ * TRIPLE;
    const unsigned short* qbase = qkvc + tokbase + h * HD + c0;
    const unsigned short* kbase = qkvc + tokbase + 2048 + h * HD + c0;
    const unsigned short* vbase = qkvc + tokbase + 4096 + h * HD + row;
    const float* abb = absig + (size_t)b * N_ * 32;
    const float* gb  = gpre + (size_t)b * N_ * INNER + h * HD + row;
    unsigned short* ob = og + (size_t)b * N_ * INNER + h * HD + row;

    float s[8];
#pragma unroll
    for (int i = 0; i < 8; ++i) s[i] = 0.f;

    uint4 kc[RCH], qc[RCH];
    float vc[RCH], ac[RCH], bc[RCH];
#pragma unroll
    for (int t = 0; t < RCH; ++t) {
        size_t o_ = (size_t)t * TRIPLE;
        kc[t] = *(const uint4*)(kbase + o_);
        qc[t] = *(const uint4*)(qbase + o_);
        vc[t] = bf2f(vbase[o_]);
        ac[t] = abb[t * 32 + h];
        bc[t] = abb[t * 32 + 16 + h];
    }

    for (int ch = 0; ch < NCH; ++ch) {
        const int np = (ch + 1 < NCH) ? ch + 1 : ch;
        uint4 kn[RCH], qn[RCH];
        float vn[RCH], an[RCH], bn[RCH];
#pragma unroll
        for (int t = 0; t < RCH; ++t) {
            size_t o_ = (size_t)(np * RCH + t) * TRIPLE;
            kn[t] = *(const uint4*)(kbase + o_);
            qn[t] = *(const uint4*)(qbase + o_);
            vn[t] = bf2f(vbase[o_]);
            an[t] = abb[(np * RCH + t) * 32 + h];
            bn[t] = abb[(np * RCH + t) * 32 + 16 + h];
        }

        float odp[RCH];
#pragma unroll
        for (int t = 0; t < RCH; ++t) {
            const float a = ac[t], bt = bc[t];
            float kf[8], qf[8];
            unpack8(kc[t], kf);
            unpack8(qc[t], qf);

            float d0 = s[0] * kf[0] + s[1] * kf[1];
            float d1 = s[2] * kf[2] + s[3] * kf[3];
            float d2 = s[4] * kf[4] + s[5] * kf[5];
            float d3 = s[6] * kf[6] + s[7] * kf[7];
            float dot = dpp_sum16((d0 + d1) + (d2 + d3));

            const float u = bt * (vc[t] - a * dot);
#pragma unroll
            for (int i = 0; i < 8; ++i) s[i] = a * s[i] + u * kf[i];

            float e0 = s[0] * qf[0] + s[1] * qf[1];
            float e1 = s[2] * qf[2] + s[3] * qf[3];
            float e2 = s[4] * qf[4] + s[5] * qf[5];
            float e3 = s[6] * qf[6] + s[7] * qf[7];
            odp[t] = (e0 + e1) + (e2 + e3);
        }

        float od[RCH];
#pragma unroll
        for (int t = 0; t < RCH; ++t) od[t] = dpp_sum16(odp[t]);

        if (lc == 0) {
#pragma unroll
            for (int t = 0; t < RCH; ++t) {
                size_t idx = (size_t)(ch * RCH + t) * INNER;
                ob[idx] = f2bf(od[t] * gb[idx]);
            }
        }

#pragma unroll
        for (int t = 0; t < RCH; ++t) {
            kc[t] = kn[t]; qc[t] = qn[t];
            vc[t] = vn[t]; ac[t] = an[t]; bc[t] = bn[t];
        }
    }
}

extern "C" void kernel_launch(void* const* d_in, const int* in_sizes, int n_in,
                              void* d_out, int out_size, void* d_ws, size_t ws_size,
                              hipStream_t stream) {
    const float* x      = (const float*)d_in[0];
    const float* W_qkv  = (const float*)d_in[1];
    const float* conv_w = (const float*)d_in[2];
    const float* W_ab   = (const float*)d_in[3];
    const float* b_ab   = (const float*)d_in[4];
    const float* W_g    = (const float*)d_in[5];
    const float* W_o    = (const float*)d_in[6];
    float* out = (float*)d_out;

    // Workspace (bytes): ~193.5 MB. ogb aliases qkv_pre (dead after conv).
    char* p = (char*)d_ws;
    unsigned short* xb      = (unsigned short*)p; p += (size_t)M_ * DM * 2;
    unsigned short* wqkvb   = (unsigned short*)p; p += (size_t)TRIPLE * DM * 2;
    unsigned short* wgb     = (unsigned short*)p; p += (size_t)INNER * DM * 2;
    unsigned short* wob     = (unsigned short*)p; p += (size_t)DM * INNER * 2;
    unsigned short* qkv_pre = (unsigned short*)p; p += (size_t)M_ * TRIPLE * 2;
    unsigned short* qkv_c   = (unsigned short*)p; p += (size_t)M_ * TRIPLE * 2;
    float*          absig   = (float*)p;          p += (size_t)M_ * 32 * 4;
    float*          gpre    = (float*)p;          p += (size_t)M_ * INNER * 4;
    unsigned short* ogb     = qkv_pre;            // alias

    dim3 blk(256);
    // casts to bf16
    cast_bf16<<<dim3((M_ * DM) / 1024), blk, 0, stream>>>(x, xb, M_ * DM);
    cast_bf16<<<dim3((TRIPLE * DM) / 1024), blk, 0, stream>>>(W_qkv, wqkvb, TRIPLE * DM);
    cast_bf16<<<dim3((INNER * DM) / 1024), blk, 0, stream>>>(W_g, wgb, INNER * DM);
    cast_bf16<<<dim3((INNER * DM) / 1024), blk, 0, stream>>>(W_o, wob, INNER * DM);

    // qkv = x @ W_qkv^T  (bf16 out)
    gemm_bf16<0, 1><<<dim3(TRIPLE / 128, M_ / 128), blk, 0, stream>>>(xb, wqkvb, qkv_pre, M_, TRIPLE, DM);
    // alpha,beta = sigmoid(x @ W_ab^T + b_ab)  (fp32, tiny)
    gemm_bt_f32<<<dim3(1, M_ / 64), blk, 0, stream>>>(x, W_ab, b_ab, absig, M_, 32, DM, 2);
    // g = silu(x @ W_g^T)  (fp32 out)
    gemm_bf16<1, 0><<<dim3(INNER / 128, M_ / 128), blk, 0, stream>>>(xb, wgb, gpre, M_, INNER, DM);
    // conv + silu + l2norm
    conv_silu_norm<<<dim3(B_ * N_), blk, 0, stream>>>(qkv_pre, conv_w, qkv_c);
    // recurrence + gating (writes bf16 og, aliases qkv_pre)
    recurrence<<<dim3(256), blk, 0, stream>>>(qkv_c, absig, gpre, ogb);
    // y = (o*g) @ W_o^T  (fp32 out)
    gemm_bf16<0, 0><<<dim3(INNER / 128, M_ / 128), blk, 0, stream>>>(ogb, wob, out, M_, INNER, DM);
}

// Round 7
// 849.753 us; speedup vs baseline: 7.6468x; 1.3763x over previous
//
#include <hip/hip_runtime.h>
#include <math.h>
#include <stddef.h>

#define B_ 2
#define N_ 2048
#define DM 2048
#define H_ 16
#define HD 128
#define INNER 2048
#define TRIPLE 6144
#define M_ (B_ * N_)   // 4096
#define T_ 32          // chunk length
#define NCHK (N_ / T_) // 64 chunks

typedef __bf16 bf16x8 __attribute__((ext_vector_type(8)));
typedef float  f32x4v __attribute__((ext_vector_type(4)));
typedef __attribute__((address_space(1))) const void gvoid;
typedef __attribute__((address_space(3))) void lvoid;

__device__ __forceinline__ float sig_(float x) { return 1.0f / (1.0f + __expf(-x)); }

__device__ __forceinline__ unsigned short f2bf(float f) {
    unsigned u = __float_as_uint(f);
    u += 0x7FFFu + ((u >> 16) & 1u);     // RNE
    return (unsigned short)(u >> 16);
}
__device__ __forceinline__ float bf2f(unsigned short h) {
    return __uint_as_float((unsigned)h << 16);
}

__global__ __launch_bounds__(256) void cast_bf16(
    const float* __restrict__ in, unsigned short* __restrict__ out, int n)
{
    int i = (blockIdx.x * 256 + threadIdx.x) * 4;
    if (i < n) {
        float4 v = *(const float4*)(in + i);
        out[i + 0] = f2bf(v.x); out[i + 1] = f2bf(v.y);
        out[i + 2] = f2bf(v.z); out[i + 3] = f2bf(v.w);
    }
}

// bf16 MFMA GEMM: C[m,n] = A[m,k] * Bw[n,k]. 128x128 tile, BK=32.
template <int ACT, int OUT_BF16>
__global__ __launch_bounds__(256) void gemm_bf16(
    const unsigned short* __restrict__ A, const unsigned short* __restrict__ Bw,
    void* __restrict__ C, int M, int N, int K)
{
    __shared__ unsigned short As[128 * 32];
    __shared__ unsigned short Bs[128 * 32];
    const int tid  = threadIdx.x;
    const int w    = tid >> 6;
    const int l    = tid & 63;
    const int row0 = blockIdx.y * 128;
    const int col0 = blockIdx.x * 128;

    const int sr = tid >> 2;
    const int sc = (tid & 3) * 8;
    const unsigned short* Ag0 = A  + (size_t)(row0 + sr) * K + sc;
    const unsigned short* Ag1 = A  + (size_t)(row0 + 64 + sr) * K + sc;
    const unsigned short* Bg0 = Bw + (size_t)(col0 + sr) * K + sc;
    const unsigned short* Bg1 = Bw + (size_t)(col0 + 64 + sr) * K + sc;
    unsigned short* AsW0 = As + w * 512;
    unsigned short* AsW1 = As + 2048 + w * 512;
    unsigned short* BsW0 = Bs + w * 512;
    unsigned short* BsW1 = Bs + 2048 + w * 512;

    f32x4v acc[4][4];
#pragma unroll
    for (int i = 0; i < 4; ++i)
#pragma unroll
        for (int j = 0; j < 4; ++j) acc[i][j] = (f32x4v){0.f, 0.f, 0.f, 0.f};

    const int m0 = (w >> 1) * 64;
    const int n0 = (w & 1) * 64;
    const int lr = l & 15;
    const int lk = (l >> 4) * 8;

    for (int k0 = 0; k0 < K; k0 += 32) {
        __syncthreads();
        __builtin_amdgcn_global_load_lds((gvoid*)(Ag0 + k0), (lvoid*)AsW0, 16, 0, 0);
        __builtin_amdgcn_global_load_lds((gvoid*)(Ag1 + k0), (lvoid*)AsW1, 16, 0, 0);
        __builtin_amdgcn_global_load_lds((gvoid*)(Bg0 + k0), (lvoid*)BsW0, 16, 0, 0);
        __builtin_amdgcn_global_load_lds((gvoid*)(Bg1 + k0), (lvoid*)BsW1, 16, 0, 0);
        __syncthreads();

        bf16x8 af[4], bfr[4];
#pragma unroll
        for (int i = 0; i < 4; ++i) {
            af[i]  = *(const bf16x8*)&As[(m0 + i * 16 + lr) * 32 + lk];
            bfr[i] = *(const bf16x8*)&Bs[(n0 + i * 16 + lr) * 32 + lk];
        }
#pragma unroll
        for (int mi = 0; mi < 4; ++mi)
#pragma unroll
            for (int ni = 0; ni < 4; ++ni)
                acc[mi][ni] = __builtin_amdgcn_mfma_f32_16x16x32_bf16(
                    af[mi], bfr[ni], acc[mi][ni], 0, 0, 0);
    }

#pragma unroll
    for (int mi = 0; mi < 4; ++mi) {
#pragma unroll
        for (int j = 0; j < 4; ++j) {
            int r = row0 + m0 + mi * 16 + (l >> 4) * 4 + j;
#pragma unroll
            for (int ni = 0; ni < 4; ++ni) {
                int c = col0 + n0 + ni * 16 + lr;
                float v = acc[mi][ni][j];
                if (ACT == 1) v = v * sig_(v);
                if (OUT_BF16) ((unsigned short*)C)[(size_t)r * N + c] = f2bf(v);
                else          ((float*)C)[(size_t)r * N + c] = v;
            }
        }
    }
}

// fp32 GEMM for the tiny ab projection (N=32)
__global__ __launch_bounds__(256) void gemm_bt_f32(
    const float* __restrict__ A, const float* __restrict__ W,
    const float* __restrict__ bias, float* __restrict__ C,
    int M, int Nn, int K, int act)
{
    __shared__ float As[16][72];
    __shared__ float Bs[16][72];
    const int tid = threadIdx.x;
    const int tx = tid & 15, ty = tid >> 4;
    const int col0 = blockIdx.x * 64;
    const int row0 = blockIdx.y * 64;
    const int lr = tid >> 2;
    const int lk = (tid & 3) * 4;

    float acc[4][4];
#pragma unroll
    for (int i = 0; i < 4; ++i)
#pragma unroll
        for (int j = 0; j < 4; ++j) acc[i][j] = 0.f;

    const float* Arow = A + (size_t)(row0 + lr) * K;
    const float* Wrow = W + (size_t)(col0 + lr) * K;
    const bool wvalid = (col0 + lr) < Nn;

    for (int k0 = 0; k0 < K; k0 += 16) {
        float4 a4 = *(const float4*)(Arow + k0 + lk);
        float4 b4 = wvalid ? *(const float4*)(Wrow + k0 + lk) : make_float4(0.f, 0.f, 0.f, 0.f);
        __syncthreads();
        As[lk + 0][lr] = a4.x; As[lk + 1][lr] = a4.y; As[lk + 2][lr] = a4.z; As[lk + 3][lr] = a4.w;
        Bs[lk + 0][lr] = b4.x; Bs[lk + 1][lr] = b4.y; Bs[lk + 2][lr] = b4.z; Bs[lk + 3][lr] = b4.w;
        __syncthreads();
#pragma unroll
        for (int kk = 0; kk < 16; ++kk) {
            float4 av = *(const float4*)&As[kk][ty * 4];
            float4 bv = *(const float4*)&Bs[kk][tx * 4];
            acc[0][0] += av.x * bv.x; acc[0][1] += av.x * bv.y; acc[0][2] += av.x * bv.z; acc[0][3] += av.x * bv.w;
            acc[1][0] += av.y * bv.x; acc[1][1] += av.y * bv.y; acc[1][2] += av.y * bv.z; acc[1][3] += av.y * bv.w;
            acc[2][0] += av.z * bv.x; acc[2][1] += av.z * bv.y; acc[2][2] += av.z * bv.z; acc[2][3] += av.z * bv.w;
            acc[3][0] += av.w * bv.x; acc[3][1] += av.w * bv.y; acc[3][2] += av.w * bv.z; acc[3][3] += av.w * bv.w;
        }
    }

#pragma unroll
    for (int i = 0; i < 4; ++i) {
        int r = row0 + ty * 4 + i;
#pragma unroll
        for (int j = 0; j < 4; ++j) {
            int c = col0 + tx * 4 + j;
            if (c < Nn) {
                float v = acc[i][j];
                if (bias) v += bias[c];
                if (act == 1) v = v * sig_(v);
                else if (act == 2) v = sig_(v);
                C[(size_t)r * Nn + c] = v;
            }
        }
    }
}

// conv(K=4, causal, depthwise) + silu + per-head l2norm of q,k. bf16 in/out.
__global__ __launch_bounds__(256) void conv_silu_norm(
    const unsigned short* __restrict__ qkv, const float* __restrict__ conv_w,
    unsigned short* __restrict__ outb)
{
    __shared__ float buf[TRIPLE];
    __shared__ float scales[32];
    const int bn = blockIdx.x;
    const int n = bn & (N_ - 1);
    const int tid = threadIdx.x;
    const unsigned short* base = qkv + (size_t)bn * TRIPLE;

    for (int c = tid; c < TRIPLE; c += 256) {
        float acc = 0.f;
#pragma unroll
        for (int j = 0; j < 4; ++j) {
            int nn = n - 3 + j;
            float xv = (nn >= 0) ? bf2f(base[(ptrdiff_t)(j - 3) * TRIPLE + c]) : 0.f;
            acc += xv * conv_w[c * 4 + j];
        }
        buf[c] = acc * sig_(acc);
    }
    __syncthreads();

    const int g = tid >> 3, l = tid & 7;
    {
        int off = (g < 16) ? g * HD : 2048 + (g - 16) * HD;
        float s = 0.f;
        for (int i = l; i < HD; i += 8) { float v = buf[off + i]; s += v * v; }
        s += __shfl_xor(s, 1); s += __shfl_xor(s, 2); s += __shfl_xor(s, 4);
        if (l == 0) scales[g] = 1.0f / fmaxf(sqrtf(s), 1e-12f);
    }
    __syncthreads();

    unsigned short* ob = outb + (size_t)bn * TRIPLE;
    for (int c = tid; c < TRIPLE; c += 256) {
        float sc = 1.f;
        if (c < 2048) sc = scales[c >> 7];
        else if (c < 4096) sc = scales[16 + ((c - 2048) >> 7)];
        ob[c] = f2bf(buf[c] * sc);
    }
}

// ---------------- chunked delta rule ----------------
// Parallel phase: per (bh, chunk): build L = tril(diag(b) decay KK^T, -1),
// solve (I+L)[Ubar | What] = [BV | diag(b P)], Mhat = tril(decay QK^T, 0),
// KhatT[e][t] = (P_last/P_t) K[t][e], P_t = prod alpha (inclusive).
__global__ __launch_bounds__(256) void chunk_prep(
    const unsigned short* __restrict__ qkvc, const float* __restrict__ absig,
    float* __restrict__ Ubar, unsigned short* __restrict__ What,
    unsigned short* __restrict__ Mhat, unsigned short* __restrict__ KhatT,
    float* __restrict__ Pbuf)
{
    __shared__ float G[T_], Pl[T_], Bl[T_];
    __shared__ float L[T_][T_ + 1];
    __shared__ float X[T_][161];
    const int bh = blockIdx.x >> 6;
    const int c  = blockIdx.x & 63;
    const int b  = bh >> 4;
    const int h  = bh & 15;
    const int tid = threadIdx.x;
    const int tok0 = c * T_;
    const size_t qbase = (size_t)b * N_ * TRIPLE;
    const unsigned short* Kb = qkvc + qbase + 2048 + h * HD;
    const unsigned short* Qb = qkvc + qbase + h * HD;
    const unsigned short* Vb = qkvc + qbase + 4096 + h * HD;
    const float* abb = absig + (size_t)b * N_ * 32;

    if (tid < T_) {
        G[tid]  = __logf(abb[(tok0 + tid) * 32 + h]);
        Bl[tid] = abb[(tok0 + tid) * 32 + 16 + h];
    }
    __syncthreads();
    if (tid == 0) {
        float run = 0.f;
        for (int t = 0; t < T_; ++t) { run += G[t]; G[t] = run; Pl[t] = __expf(run); }
    }
    __syncthreads();
    if (tid < T_) Pbuf[((size_t)bh * NCHK + c) * T_ + tid] = Pl[tid];

    const int w = tid >> 6, lane = tid & 63;
    const int lr = lane & 15, lk8 = (lane >> 4) * 8, lrow4 = (lane >> 4) * 4;
    const int mt = w >> 1, nt = w & 1;

    // KK = K K^T, QK = Q K^T  (wave w owns tile (mt, nt))
    f32x4v akk = {0.f,0.f,0.f,0.f}, aqk = {0.f,0.f,0.f,0.f};
    const unsigned short* Km = Kb + (size_t)(tok0 + mt * 16 + lr) * TRIPLE;
    const unsigned short* Qm = Qb + (size_t)(tok0 + mt * 16 + lr) * TRIPLE;
    const unsigned short* Kn = Kb + (size_t)(tok0 + nt * 16 + lr) * TRIPLE;
#pragma unroll
    for (int ks = 0; ks < 4; ++ks) {
        bf16x8 aK = *(const bf16x8*)(Km + ks * 32 + lk8);
        bf16x8 aQ = *(const bf16x8*)(Qm + ks * 32 + lk8);
        bf16x8 bK = *(const bf16x8*)(Kn + ks * 32 + lk8);
        akk = __builtin_amdgcn_mfma_f32_16x16x32_bf16(aK, bK, akk, 0, 0, 0);
        aqk = __builtin_amdgcn_mfma_f32_16x16x32_bf16(aQ, bK, aqk, 0, 0, 0);
    }
    unsigned short* Mg = Mhat + ((size_t)bh * NCHK + c) * (T_ * T_);
#pragma unroll
    for (int reg = 0; reg < 4; ++reg) {
        int t = mt * 16 + lrow4 + reg;
        int i = nt * 16 + lr;
        float dec = __expf(G[t] - G[i]);
        L[t][i] = (i < t) ? Bl[t] * dec * akk[reg] : 0.f;
        Mg[t * T_ + i] = (i <= t) ? f2bf(dec * aqk[reg]) : (unsigned short)0;
    }
    __syncthreads();

    // X = [ B V | diag(B P) ]
    for (int idx = tid; idx < T_ * HD; idx += 256) {
        int t = idx >> 7, e = idx & 127;
        X[t][e] = Bl[t] * bf2f(Vb[(size_t)(tok0 + t) * TRIPLE + e]);
    }
    for (int idx = tid; idx < T_ * T_; idx += 256) {
        int t = idx >> 5, i = idx & 31;
        X[t][HD + i] = (i == t) ? Bl[t] * Pl[t] : 0.f;
    }
    __syncthreads();

    // forward substitution: (I+L) X = RHS, thread tid owns column tid
    if (tid < HD + T_) {
        float x[T_];
#pragma unroll
        for (int t = 0; t < T_; ++t) x[t] = X[t][tid];
#pragma unroll
        for (int t = 1; t < T_; ++t)
#pragma unroll
            for (int i = 0; i < t; ++i)
                x[t] -= L[t][i] * x[i];
        if (tid < HD) {
            float* Ug = Ubar + ((size_t)bh * NCHK + c) * (T_ * HD);
#pragma unroll
            for (int t = 0; t < T_; ++t) Ug[t * HD + tid] = x[t];
        } else {
            unsigned short* Wg = What + ((size_t)bh * NCHK + c) * (T_ * T_);
#pragma unroll
            for (int t = 0; t < T_; ++t) Wg[t * T_ + (tid - HD)] = f2bf(x[t]);
        }
    }

    // KhatT[e][t] = exp(G_last - G_t) * K[t][e]
    unsigned short* Kg = KhatT + ((size_t)bh * NCHK + c) * (HD * T_);
    for (int idx = tid; idx < HD * T_; idx += 256) {
        int e = idx >> 5, t = idx & 31;
        float v = __expf(G[T_ - 1] - G[t]) * bf2f(Kb[(size_t)(tok0 + t) * TRIPLE + e]);
        Kg[idx] = f2bf(v);
    }
}

// Serial phase: 128 blocks = 32 bh x 4 d-slices of 32 state rows. Loops 64
// chunks: C = K S0^T (bf16 hi+lo split), U = Ubar - What C, O = P C' + Mhat U,
// S = gamma S + U^T Khat. S fp32 in LDS throughout.
__global__ __launch_bounds__(256) void chunk_scan(
    const unsigned short* __restrict__ qkvc, const float* __restrict__ gpre,
    const float* __restrict__ Ubar, const unsigned short* __restrict__ What,
    const unsigned short* __restrict__ Mhat, const unsigned short* __restrict__ KhatT,
    const float* __restrict__ Pbuf, unsigned short* __restrict__ og)
{
    __shared__ float S[32 * 132];          // [d][e], stride 132 (16B-aligned, 2-way banks)
    __shared__ unsigned short CT[32 * 40]; // [d][t], holds -C
    __shared__ unsigned short UT[32 * 40]; // [d][t]
    const int blk = blockIdx.x;
    const int bh  = blk & 31;              // same-XCD clustering for K/Q reuse
    const int dsl = blk >> 5;
    const int b = bh >> 4, h = bh & 15;
    const int d0 = dsl * 32;
    const int tid = threadIdx.x;
    const int w = tid >> 6, lane = tid & 63;
    const int lr = lane & 15, lk8 = (lane >> 4) * 8, lrow4 = (lane >> 4) * 4;
    const int mt = w >> 1, nt = w & 1;

    for (int i = tid; i < 32 * 132; i += 256) S[i] = 0.f;

    const size_t qbase = (size_t)b * N_ * TRIPLE;
    const unsigned short* Kb = qkvc + qbase + 2048 + h * HD;
    const unsigned short* Qb = qkvc + qbase + h * HD;
    const float* gb = gpre + (size_t)b * N_ * INNER + h * HD;
    unsigned short* ogb = og + (size_t)b * N_ * INNER + h * HD;
    __syncthreads();

    for (int c = 0; c < NCHK; ++c) {
        const int tok0 = c * T_;
        const size_t cb = (size_t)bh * NCHK + c;

        // ---- stage B: C = K S0^T, C' = Q S0^T (hi/lo split of S0) ----
        f32x4v accC = {0.f,0.f,0.f,0.f}, accP = {0.f,0.f,0.f,0.f};
        const unsigned short* Km = Kb + (size_t)(tok0 + mt * 16 + lr) * TRIPLE;
        const unsigned short* Qm = Qb + (size_t)(tok0 + mt * 16 + lr) * TRIPLE;
        const int drow = nt * 16 + lr;
#pragma unroll
        for (int ks = 0; ks < 4; ++ks) {
            bf16x8 aK = *(const bf16x8*)(Km + ks * 32 + lk8);
            bf16x8 aQ = *(const bf16x8*)(Qm + ks * 32 + lk8);
            const float* sp = &S[drow * 132 + ks * 32 + lk8];
            float4 f0 = *(const float4*)sp;
            float4 f1 = *(const float4*)(sp + 4);
            float ff[8] = {f0.x, f0.y, f0.z, f0.w, f1.x, f1.y, f1.z, f1.w};
            union { bf16x8 v; unsigned short u[8]; } hi, lo;
#pragma unroll
            for (int j = 0; j < 8; ++j) {
                unsigned short hh = f2bf(ff[j]);
                hi.u[j] = hh;
                lo.u[j] = f2bf(ff[j] - bf2f(hh));
            }
            accC = __builtin_amdgcn_mfma_f32_16x16x32_bf16(aK, hi.v, accC, 0, 0, 0);
            accC = __builtin_amdgcn_mfma_f32_16x16x32_bf16(aK, lo.v, accC, 0, 0, 0);
            accP = __builtin_amdgcn_mfma_f32_16x16x32_bf16(aQ, hi.v, accP, 0, 0, 0);
            accP = __builtin_amdgcn_mfma_f32_16x16x32_bf16(aQ, lo.v, accP, 0, 0, 0);
        }
        {   // CT[d][t] = -C  (acc: col=lane&15 -> d, row=lrow4+reg -> t)
            ushort4 cv;
            cv.x = f2bf(-accC[0]); cv.y = f2bf(-accC[1]);
            cv.z = f2bf(-accC[2]); cv.w = f2bf(-accC[3]);
            *(ushort4*)&CT[(nt * 16 + lr) * 40 + mt * 16 + lrow4] = cv;
        }
        __syncthreads();

        // ---- stage D: U = Ubar + What @ (-C) ----
        f32x4v accU;
        {
            const float* Ug = Ubar + cb * (T_ * HD);
#pragma unroll
            for (int reg = 0; reg < 4; ++reg)
                accU[reg] = Ug[(mt * 16 + lrow4 + reg) * HD + d0 + nt * 16 + lr];
            bf16x8 aW = *(const bf16x8*)(What + cb * (T_ * T_) + (mt * 16 + lr) * T_ + lk8);
            bf16x8 bC = *(const bf16x8*)&CT[(nt * 16 + lr) * 40 + lk8];
            accU = __builtin_amdgcn_mfma_f32_16x16x32_bf16(aW, bC, accU, 0, 0, 0);
        }
        {
            ushort4 uv;
            uv.x = f2bf(accU[0]); uv.y = f2bf(accU[1]);
            uv.z = f2bf(accU[2]); uv.w = f2bf(accU[3]);
            *(ushort4*)&UT[(nt * 16 + lr) * 40 + mt * 16 + lrow4] = uv;
        }
        __syncthreads();

        // ---- stage E: O = diag(P) C' + Mhat @ U ----
        const float* Pg = Pbuf + cb * T_;
        {
            f32x4v accO;
#pragma unroll
            for (int reg = 0; reg < 4; ++reg)
                accO[reg] = Pg[mt * 16 + lrow4 + reg] * accP[reg];
            bf16x8 aM = *(const bf16x8*)(Mhat + cb * (T_ * T_) + (mt * 16 + lr) * T_ + lk8);
            bf16x8 bU = *(const bf16x8*)&UT[(nt * 16 + lr) * 40 + lk8];
            accO = __builtin_amdgcn_mfma_f32_16x16x32_bf16(aM, bU, accO, 0, 0, 0);
#pragma unroll
            for (int reg = 0; reg < 4; ++reg) {
                int tok = tok0 + mt * 16 + lrow4 + reg;
                size_t idx = (size_t)tok * INNER + d0 + nt * 16 + lr;
                ogb[idx] = f2bf(accO[reg] * gb[idx]);
            }
        }

        // ---- stage F: S = gamma*S + U^T @ KhatT^T ----
        {
            float gam = Pg[T_ - 1];
            const unsigned short* Kh = KhatT + cb * (HD * T_);
            bf16x8 aU = *(const bf16x8*)&UT[(mt * 16 + lr) * 40 + lk8];  // m=d, k=t
#pragma unroll
            for (int j = 0; j < 4; ++j) {
                int ntS = (w & 1) * 4 + j;
                f32x4v accS;
#pragma unroll
                for (int reg = 0; reg < 4; ++reg)
                    accS[reg] = gam * S[(mt * 16 + lrow4 + reg) * 132 + ntS * 16 + lr];
                bf16x8 bK = *(const bf16x8*)(Kh + (ntS * 16 + lr) * T_ + lk8);
                accS = __builtin_amdgcn_mfma_f32_16x16x32_bf16(aU, bK, accS, 0, 0, 0);
#pragma unroll
                for (int reg = 0; reg < 4; ++reg)
                    S[(mt * 16 + lrow4 + reg) * 132 + ntS * 16 + lr] = accS[reg];
            }
        }
        __syncthreads();
    }
}

extern "C" void kernel_launch(void* const* d_in, const int* in_sizes, int n_in,
                              void* d_out, int out_size, void* d_ws, size_t ws_size,
                              hipStream_t stream) {
    const float* x      = (const float*)d_in[0];
    const float* W_qkv  = (const float*)d_in[1];
    const float* conv_w = (const float*)d_in[2];
    const float* W_ab   = (const float*)d_in[3];
    const float* b_ab   = (const float*)d_in[4];
    const float* W_g    = (const float*)d_in[5];
    const float* W_o    = (const float*)d_in[6];
    float* out = (float*)d_out;

    // Layout (bytes). xb..qkv_pre form a contiguous 67.1MB region that is
    // dead after conv -> overlaid by the chunk buffers (59MB). Total ~210MB.
    char* p = (char*)d_ws;
    unsigned short* wqkvb   = (unsigned short*)p; p += (size_t)TRIPLE * DM * 2;
    unsigned short* wgb     = (unsigned short*)p; p += (size_t)INNER * DM * 2;
    unsigned short* wob     = (unsigned short*)p; p += (size_t)DM * INNER * 2;
    unsigned short* xb      = (unsigned short*)p; p += (size_t)M_ * DM * 2;
    unsigned short* qkv_pre = (unsigned short*)p; p += (size_t)M_ * TRIPLE * 2;
    unsigned short* qkv_c   = (unsigned short*)p; p += (size_t)M_ * TRIPLE * 2;
    float*          absig   = (float*)p;          p += (size_t)M_ * 32 * 4;
    float*          gpre    = (float*)p;          p += (size_t)M_ * INNER * 4;
    unsigned short* ogb     = (unsigned short*)p; p += (size_t)M_ * INNER * 2;

    // chunk buffers overlay xb+qkv_pre
    char* q = (char*)xb;
    float*          Ubar  = (float*)q;          q += (size_t)32 * NCHK * T_ * HD * 4;  // 33.5MB
    unsigned short* KhatT = (unsigned short*)q; q += (size_t)32 * NCHK * HD * T_ * 2;  // 16.8MB
    unsigned short* What  = (unsigned short*)q; q += (size_t)32 * NCHK * T_ * T_ * 2;  // 4.2MB
    unsigned short* Mhat  = (unsigned short*)q; q += (size_t)32 * NCHK * T_ * T_ * 2;  // 4.2MB
    float*          Pbuf  = (float*)q;          q += (size_t)32 * NCHK * T_ * 4;       // 0.26MB

    dim3 blk(256);
    cast_bf16<<<dim3((M_ * DM) / 1024), blk, 0, stream>>>(x, xb, M_ * DM);
    cast_bf16<<<dim3((TRIPLE * DM) / 1024), blk, 0, stream>>>(W_qkv, wqkvb, TRIPLE * DM);
    cast_bf16<<<dim3((INNER * DM) / 1024), blk, 0, stream>>>(W_g, wgb, INNER * DM);
    cast_bf16<<<dim3((INNER * DM) / 1024), blk, 0, stream>>>(W_o, wob, INNER * DM);

    gemm_bf16<0, 1><<<dim3(TRIPLE / 128, M_ / 128), blk, 0, stream>>>(xb, wqkvb, qkv_pre, M_, TRIPLE, DM);
    gemm_bt_f32<<<dim3(1, M_ / 64), blk, 0, stream>>>(x, W_ab, b_ab, absig, M_, 32, DM, 2);
    gemm_bf16<1, 0><<<dim3(INNER / 128, M_ / 128), blk, 0, stream>>>(xb, wgb, gpre, M_, INNER, DM);
    conv_silu_norm<<<dim3(B_ * N_), blk, 0, stream>>>(qkv_pre, conv_w, qkv_c);

    chunk_prep<<<dim3(32 * NCHK), blk, 0, stream>>>(qkv_c, absig, Ubar, What, Mhat, KhatT, Pbuf);
    chunk_scan<<<dim3(128), blk, 0, stream>>>(qkv_c, gpre, Ubar, What, Mhat, KhatT, Pbuf, ogb);

    gemm_bf16<0, 0><<<dim3(INNER / 128, M_ / 128), blk, 0, stream>>>(ogb, wob, out, M_, INNER, DM);
}

// Round 8
// 759.073 us; speedup vs baseline: 8.5603x; 1.1195x over previous
//
#include <hip/hip_runtime.h>
#include <math.h>
#include <stddef.h>

#define B_ 2
#define N_ 2048
#define DM 2048
#define H_ 16
#define HD 128
#define INNER 2048
#define TRIPLE 6144
#define M_ (B_ * N_)   // 4096
#define T_ 32          // chunk length
#define NCHK (N_ / T_) // 64 chunks

typedef __bf16 bf16x8 __attribute__((ext_vector_type(8)));
typedef float  f32x4v __attribute__((ext_vector_type(4)));
typedef __attribute__((address_space(1))) const void gvoid;
typedef __attribute__((address_space(3))) void lvoid;

__device__ __forceinline__ float sig_(float x) { return 1.0f / (1.0f + __expf(-x)); }

__device__ __forceinline__ unsigned short f2bf(float f) {
    unsigned u = __float_as_uint(f);
    u += 0x7FFFu + ((u >> 16) & 1u);     // RNE
    return (unsigned short)(u >> 16);
}
__device__ __forceinline__ float bf2f(unsigned short h) {
    return __uint_as_float((unsigned)h << 16);
}

// Workgroup barrier that waits ONLY on LDS ops (lgkmcnt(0)); prefetched
// global loads stay in flight across it. 0xC07F = vmcnt(63) expcnt(7) lgkmcnt(0).
__device__ __forceinline__ void lds_barrier() {
    asm volatile("" ::: "memory");
    __builtin_amdgcn_s_waitcnt(0xC07F);
    __builtin_amdgcn_s_barrier();
    asm volatile("" ::: "memory");
}

__global__ __launch_bounds__(256) void cast_bf16(
    const float* __restrict__ in, unsigned short* __restrict__ out, int n)
{
    int i = (blockIdx.x * 256 + threadIdx.x) * 4;
    if (i < n) {
        float4 v = *(const float4*)(in + i);
        out[i + 0] = f2bf(v.x); out[i + 1] = f2bf(v.y);
        out[i + 2] = f2bf(v.z); out[i + 3] = f2bf(v.w);
    }
}

// bf16 MFMA GEMM: C[m,n] = A[m,k] * Bw[n,k]. 128x128 tile, BK=32.
template <int ACT, int OUT_BF16>
__global__ __launch_bounds__(256) void gemm_bf16(
    const unsigned short* __restrict__ A, const unsigned short* __restrict__ Bw,
    void* __restrict__ C, int M, int N, int K)
{
    __shared__ unsigned short As[128 * 32];
    __shared__ unsigned short Bs[128 * 32];
    const int tid  = threadIdx.x;
    const int w    = tid >> 6;
    const int l    = tid & 63;
    const int row0 = blockIdx.y * 128;
    const int col0 = blockIdx.x * 128;

    const int sr = tid >> 2;
    const int sc = (tid & 3) * 8;
    const unsigned short* Ag0 = A  + (size_t)(row0 + sr) * K + sc;
    const unsigned short* Ag1 = A  + (size_t)(row0 + 64 + sr) * K + sc;
    const unsigned short* Bg0 = Bw + (size_t)(col0 + sr) * K + sc;
    const unsigned short* Bg1 = Bw + (size_t)(col0 + 64 + sr) * K + sc;
    unsigned short* AsW0 = As + w * 512;
    unsigned short* AsW1 = As + 2048 + w * 512;
    unsigned short* BsW0 = Bs + w * 512;
    unsigned short* BsW1 = Bs + 2048 + w * 512;

    f32x4v acc[4][4];
#pragma unroll
    for (int i = 0; i < 4; ++i)
#pragma unroll
        for (int j = 0; j < 4; ++j) acc[i][j] = (f32x4v){0.f, 0.f, 0.f, 0.f};

    const int m0 = (w >> 1) * 64;
    const int n0 = (w & 1) * 64;
    const int lr = l & 15;
    const int lk = (l >> 4) * 8;

    for (int k0 = 0; k0 < K; k0 += 32) {
        __syncthreads();
        __builtin_amdgcn_global_load_lds((gvoid*)(Ag0 + k0), (lvoid*)AsW0, 16, 0, 0);
        __builtin_amdgcn_global_load_lds((gvoid*)(Ag1 + k0), (lvoid*)AsW1, 16, 0, 0);
        __builtin_amdgcn_global_load_lds((gvoid*)(Bg0 + k0), (lvoid*)BsW0, 16, 0, 0);
        __builtin_amdgcn_global_load_lds((gvoid*)(Bg1 + k0), (lvoid*)BsW1, 16, 0, 0);
        __syncthreads();

        bf16x8 af[4], bfr[4];
#pragma unroll
        for (int i = 0; i < 4; ++i) {
            af[i]  = *(const bf16x8*)&As[(m0 + i * 16 + lr) * 32 + lk];
            bfr[i] = *(const bf16x8*)&Bs[(n0 + i * 16 + lr) * 32 + lk];
        }
#pragma unroll
        for (int mi = 0; mi < 4; ++mi)
#pragma unroll
            for (int ni = 0; ni < 4; ++ni)
                acc[mi][ni] = __builtin_amdgcn_mfma_f32_16x16x32_bf16(
                    af[mi], bfr[ni], acc[mi][ni], 0, 0, 0);
    }

#pragma unroll
    for (int mi = 0; mi < 4; ++mi) {
#pragma unroll
        for (int j = 0; j < 4; ++j) {
            int r = row0 + m0 + mi * 16 + (l >> 4) * 4 + j;
#pragma unroll
            for (int ni = 0; ni < 4; ++ni) {
                int c = col0 + n0 + ni * 16 + lr;
                float v = acc[mi][ni][j];
                if (ACT == 1) v = v * sig_(v);
                if (OUT_BF16) ((unsigned short*)C)[(size_t)r * N + c] = f2bf(v);
                else          ((float*)C)[(size_t)r * N + c] = v;
            }
        }
    }
}

// fp32 GEMM for the tiny ab projection (N=32)
__global__ __launch_bounds__(256) void gemm_bt_f32(
    const float* __restrict__ A, const float* __restrict__ W,
    const float* __restrict__ bias, float* __restrict__ C,
    int M, int Nn, int K, int act)
{
    __shared__ float As[16][72];
    __shared__ float Bs[16][72];
    const int tid = threadIdx.x;
    const int tx = tid & 15, ty = tid >> 4;
    const int col0 = blockIdx.x * 64;
    const int row0 = blockIdx.y * 64;
    const int lr = tid >> 2;
    const int lk = (tid & 3) * 4;

    float acc[4][4];
#pragma unroll
    for (int i = 0; i < 4; ++i)
#pragma unroll
        for (int j = 0; j < 4; ++j) acc[i][j] = 0.f;

    const float* Arow = A + (size_t)(row0 + lr) * K;
    const float* Wrow = W + (size_t)(col0 + lr) * K;
    const bool wvalid = (col0 + lr) < Nn;

    for (int k0 = 0; k0 < K; k0 += 16) {
        float4 a4 = *(const float4*)(Arow + k0 + lk);
        float4 b4 = wvalid ? *(const float4*)(Wrow + k0 + lk) : make_float4(0.f, 0.f, 0.f, 0.f);
        __syncthreads();
        As[lk + 0][lr] = a4.x; As[lk + 1][lr] = a4.y; As[lk + 2][lr] = a4.z; As[lk + 3][lr] = a4.w;
        Bs[lk + 0][lr] = b4.x; Bs[lk + 1][lr] = b4.y; Bs[lk + 2][lr] = b4.z; Bs[lk + 3][lr] = b4.w;
        __syncthreads();
#pragma unroll
        for (int kk = 0; kk < 16; ++kk) {
            float4 av = *(const float4*)&As[kk][ty * 4];
            float4 bv = *(const float4*)&Bs[kk][tx * 4];
            acc[0][0] += av.x * bv.x; acc[0][1] += av.x * bv.y; acc[0][2] += av.x * bv.z; acc[0][3] += av.x * bv.w;
            acc[1][0] += av.y * bv.x; acc[1][1] += av.y * bv.y; acc[1][2] += av.y * bv.z; acc[1][3] += av.y * bv.w;
            acc[2][0] += av.z * bv.x; acc[2][1] += av.z * bv.y; acc[2][2] += av.z * bv.z; acc[2][3] += av.z * bv.w;
            acc[3][0] += av.w * bv.x; acc[3][1] += av.w * bv.y; acc[3][2] += av.w * bv.z; acc[3][3] += av.w * bv.w;
        }
    }

#pragma unroll
    for (int i = 0; i < 4; ++i) {
        int r = row0 + ty * 4 + i;
#pragma unroll
        for (int j = 0; j < 4; ++j) {
            int c = col0 + tx * 4 + j;
            if (c < Nn) {
                float v = acc[i][j];
                if (bias) v += bias[c];
                if (act == 1) v = v * sig_(v);
                else if (act == 2) v = sig_(v);
                C[(size_t)r * Nn + c] = v;
            }
        }
    }
}

// conv(K=4, causal, depthwise) + silu + per-head l2norm of q,k. bf16 in/out.
__global__ __launch_bounds__(256) void conv_silu_norm(
    const unsigned short* __restrict__ qkv, const float* __restrict__ conv_w,
    unsigned short* __restrict__ outb)
{
    __shared__ float buf[TRIPLE];
    __shared__ float scales[32];
    const int bn = blockIdx.x;
    const int n = bn & (N_ - 1);
    const int tid = threadIdx.x;
    const unsigned short* base = qkv + (size_t)bn * TRIPLE;

    for (int c = tid; c < TRIPLE; c += 256) {
        float acc = 0.f;
#pragma unroll
        for (int j = 0; j < 4; ++j) {
            int nn = n - 3 + j;
            float xv = (nn >= 0) ? bf2f(base[(ptrdiff_t)(j - 3) * TRIPLE + c]) : 0.f;
            acc += xv * conv_w[c * 4 + j];
        }
        buf[c] = acc * sig_(acc);
    }
    __syncthreads();

    const int g = tid >> 3, l = tid & 7;
    {
        int off = (g < 16) ? g * HD : 2048 + (g - 16) * HD;
        float s = 0.f;
        for (int i = l; i < HD; i += 8) { float v = buf[off + i]; s += v * v; }
        s += __shfl_xor(s, 1); s += __shfl_xor(s, 2); s += __shfl_xor(s, 4);
        if (l == 0) scales[g] = 1.0f / fmaxf(sqrtf(s), 1e-12f);
    }
    __syncthreads();

    unsigned short* ob = outb + (size_t)bn * TRIPLE;
    for (int c = tid; c < TRIPLE; c += 256) {
        float sc = 1.f;
        if (c < 2048) sc = scales[c >> 7];
        else if (c < 4096) sc = scales[16 + ((c - 2048) >> 7)];
        ob[c] = f2bf(buf[c] * sc);
    }
}

// ---------------- chunked delta rule ----------------
// Parallel phase (unchanged from R7).
__global__ __launch_bounds__(256) void chunk_prep(
    const unsigned short* __restrict__ qkvc, const float* __restrict__ absig,
    float* __restrict__ Ubar, unsigned short* __restrict__ What,
    unsigned short* __restrict__ Mhat, unsigned short* __restrict__ KhatT,
    float* __restrict__ Pbuf)
{
    __shared__ float G[T_], Pl[T_], Bl[T_];
    __shared__ float L[T_][T_ + 1];
    __shared__ float X[T_][161];
    const int bh = blockIdx.x >> 6;
    const int c  = blockIdx.x & 63;
    const int b  = bh >> 4;
    const int h  = bh & 15;
    const int tid = threadIdx.x;
    const int tok0 = c * T_;
    const size_t qbase = (size_t)b * N_ * TRIPLE;
    const unsigned short* Kb = qkvc + qbase + 2048 + h * HD;
    const unsigned short* Qb = qkvc + qbase + h * HD;
    const unsigned short* Vb = qkvc + qbase + 4096 + h * HD;
    const float* abb = absig + (size_t)b * N_ * 32;

    if (tid < T_) {
        G[tid]  = __logf(abb[(tok0 + tid) * 32 + h]);
        Bl[tid] = abb[(tok0 + tid) * 32 + 16 + h];
    }
    __syncthreads();
    if (tid == 0) {
        float run = 0.f;
        for (int t = 0; t < T_; ++t) { run += G[t]; G[t] = run; Pl[t] = __expf(run); }
    }
    __syncthreads();
    if (tid < T_) Pbuf[((size_t)bh * NCHK + c) * T_ + tid] = Pl[tid];

    const int w = tid >> 6, lane = tid & 63;
    const int lr = lane & 15, lk8 = (lane >> 4) * 8, lrow4 = (lane >> 4) * 4;
    const int mt = w >> 1, nt = w & 1;

    f32x4v akk = {0.f,0.f,0.f,0.f}, aqk = {0.f,0.f,0.f,0.f};
    const unsigned short* Km = Kb + (size_t)(tok0 + mt * 16 + lr) * TRIPLE;
    const unsigned short* Qm = Qb + (size_t)(tok0 + mt * 16 + lr) * TRIPLE;
    const unsigned short* Kn = Kb + (size_t)(tok0 + nt * 16 + lr) * TRIPLE;
#pragma unroll
    for (int ks = 0; ks < 4; ++ks) {
        bf16x8 aK = *(const bf16x8*)(Km + ks * 32 + lk8);
        bf16x8 aQ = *(const bf16x8*)(Qm + ks * 32 + lk8);
        bf16x8 bK = *(const bf16x8*)(Kn + ks * 32 + lk8);
        akk = __builtin_amdgcn_mfma_f32_16x16x32_bf16(aK, bK, akk, 0, 0, 0);
        aqk = __builtin_amdgcn_mfma_f32_16x16x32_bf16(aQ, bK, aqk, 0, 0, 0);
    }
    unsigned short* Mg = Mhat + ((size_t)bh * NCHK + c) * (T_ * T_);
#pragma unroll
    for (int reg = 0; reg < 4; ++reg) {
        int t = mt * 16 + lrow4 + reg;
        int i = nt * 16 + lr;
        float dec = __expf(G[t] - G[i]);
        L[t][i] = (i < t) ? Bl[t] * dec * akk[reg] : 0.f;
        Mg[t * T_ + i] = (i <= t) ? f2bf(dec * aqk[reg]) : (unsigned short)0;
    }
    __syncthreads();

    for (int idx = tid; idx < T_ * HD; idx += 256) {
        int t = idx >> 7, e = idx & 127;
        X[t][e] = Bl[t] * bf2f(Vb[(size_t)(tok0 + t) * TRIPLE + e]);
    }
    for (int idx = tid; idx < T_ * T_; idx += 256) {
        int t = idx >> 5, i = idx & 31;
        X[t][HD + i] = (i == t) ? Bl[t] * Pl[t] : 0.f;
    }
    __syncthreads();

    if (tid < HD + T_) {
        float x[T_];
#pragma unroll
        for (int t = 0; t < T_; ++t) x[t] = X[t][tid];
#pragma unroll
        for (int t = 1; t < T_; ++t)
#pragma unroll
            for (int i = 0; i < t; ++i)
                x[t] -= L[t][i] * x[i];
        if (tid < HD) {
            float* Ug = Ubar + ((size_t)bh * NCHK + c) * (T_ * HD);
#pragma unroll
            for (int t = 0; t < T_; ++t) Ug[t * HD + tid] = x[t];
        } else {
            unsigned short* Wg = What + ((size_t)bh * NCHK + c) * (T_ * T_);
#pragma unroll
            for (int t = 0; t < T_; ++t) Wg[t * T_ + (tid - HD)] = f2bf(x[t]);
        }
    }

    unsigned short* Kg = KhatT + ((size_t)bh * NCHK + c) * (HD * T_);
    for (int idx = tid; idx < HD * T_; idx += 256) {
        int e = idx >> 5, t = idx & 31;
        float v = __expf(G[T_ - 1] - G[t]) * bf2f(Kb[(size_t)(tok0 + t) * TRIPLE + e]);
        Kg[idx] = f2bf(v);
    }
}

// Serial phase, restructured: 256 blocks = 32 bh x 8 d-slices of 16 rows.
// All global operands register-prefetched one chunk ahead; lgkmcnt-only
// barriers keep prefetch loads in flight; S hi/lo split maintained in LDS
// by stage F (off stage B's critical path).
// Wave roles: w0/w2: B(K,mt=w>>1)+D(mt);  w1/w3: B(Q,mt)+E(mt);  all: F.
__global__ __launch_bounds__(256) void chunk_scan(
    const unsigned short* __restrict__ qkvc, const float* __restrict__ gpre,
    const float* __restrict__ Ubar, const unsigned short* __restrict__ What,
    const unsigned short* __restrict__ Mhat, const unsigned short* __restrict__ KhatT,
    const float* __restrict__ Pbuf, unsigned short* __restrict__ og)
{
    __shared__ float          S  [16 * 132];   // fp32 state rows
    __shared__ unsigned short Shi[16 * 136];   // bf16 hi of S
    __shared__ unsigned short Slo[16 * 136];   // bf16 lo of S
    __shared__ unsigned short CT [16 * 40];    // -C  [d][t]
    __shared__ unsigned short UT [16 * 40];    // U   [d][t]

    const int blk = blockIdx.x;
    const int bh  = blk & 31;              // same-XCD clustering per bh
    const int dsl = blk >> 5;              // 0..7
    const int b = bh >> 4, h = bh & 15;
    const int d0 = dsl * 16;
    const int tid = threadIdx.x;
    const int w = tid >> 6, lane = tid & 63;
    const int lr = lane & 15, lk8 = (lane >> 4) * 8, lrow4 = (lane >> 4) * 4;
    const int mt = w >> 1;                 // t-tile for B/D/E
    const bool isQ = (w & 1);              // waves 1,3 compute Q-side

    for (int i = tid; i < 16 * 132; i += 256) S[i] = 0.f;
    for (int i = tid; i < 16 * 136; i += 256) { Shi[i] = 0; Slo[i] = 0; }

    const size_t qbase = (size_t)b * N_ * TRIPLE;
    const unsigned short* Ab = qkvc + qbase + (isQ ? 0 : 2048) + h * HD; // K or Q rows
    const float* gb = gpre + (size_t)b * N_ * INNER + h * HD;
    unsigned short* ogb = og + (size_t)b * N_ * INNER + h * HD;

    // ---- prefetch chunk 0 ----
    bf16x8 aF[4];            // A-frag (K or Q rows, t-tile mt)
    bf16x8 wmF;              // What (w0/w2) or Mhat (w1/w3) frag
    float  sc4[4];           // Ubar addend (w0/w2) or P decay (w1/w3)
    float  g4[4];            // gpre gate values (w1/w3)
    bf16x8 khF[2];           // Khat frags for F (e-tiles 2w, 2w+1)
    float  gam;              // P[T-1]
    {
        const size_t cb = (size_t)bh * NCHK;
        const unsigned short* Am = Ab + (size_t)(mt * 16 + lr) * TRIPLE;
#pragma unroll
        for (int ks = 0; ks < 4; ++ks) aF[ks] = *(const bf16x8*)(Am + ks * 32 + lk8);
        if (!isQ) {
            wmF = *(const bf16x8*)(What + cb * (T_*T_) + (mt * 16 + lr) * T_ + lk8);
#pragma unroll
            for (int j = 0; j < 4; ++j)
                sc4[j] = Ubar[cb * (T_*HD) + (mt * 16 + lrow4 + j) * HD + d0 + lr];
        } else {
            wmF = *(const bf16x8*)(Mhat + cb * (T_*T_) + (mt * 16 + lr) * T_ + lk8);
#pragma unroll
            for (int j = 0; j < 4; ++j) {
                sc4[j] = Pbuf[cb * T_ + mt * 16 + lrow4 + j];
                g4[j]  = gb[(size_t)(mt * 16 + lrow4 + j) * INNER + d0 + lr];
            }
        }
#pragma unroll
        for (int j2 = 0; j2 < 2; ++j2)
            khF[j2] = *(const bf16x8*)(KhatT + cb * (HD*T_) + ((2*w + j2) * 16 + lr) * T_ + lk8);
        gam = Pbuf[cb * T_ + T_ - 1];
    }
    __syncthreads();

    for (int c = 0; c < NCHK; ++c) {
        // ---- issue prefetch for chunk c+1 (independent of everything) ----
        const int np = (c + 1 < NCHK) ? c + 1 : c;
        const size_t cbn = (size_t)bh * NCHK + np;
        const int tok0n = np * T_;
        bf16x8 aFn[4], wmFn, khFn[2];
        float sc4n[4], g4n[4], gamn;
        {
            const unsigned short* Am = Ab + (size_t)(tok0n + mt * 16 + lr) * TRIPLE;
#pragma unroll
            for (int ks = 0; ks < 4; ++ks) aFn[ks] = *(const bf16x8*)(Am + ks * 32 + lk8);
            if (!isQ) {
                wmFn = *(const bf16x8*)(What + cbn * (T_*T_) + (mt * 16 + lr) * T_ + lk8);
#pragma unroll
                for (int j = 0; j < 4; ++j)
                    sc4n[j] = Ubar[cbn * (T_*HD) + (mt * 16 + lrow4 + j) * HD + d0 + lr];
            } else {
                wmFn = *(const bf16x8*)(Mhat + cbn * (T_*T_) + (mt * 16 + lr) * T_ + lk8);
#pragma unroll
                for (int j = 0; j < 4; ++j) {
                    sc4n[j] = Pbuf[cbn * T_ + mt * 16 + lrow4 + j];
                    g4n[j]  = gb[(size_t)(tok0n + mt * 16 + lrow4 + j) * INNER + d0 + lr];
                }
            }
#pragma unroll
            for (int j2 = 0; j2 < 2; ++j2)
                khFn[j2] = *(const bf16x8*)(KhatT + cbn * (HD*T_) + ((2*w + j2) * 16 + lr) * T_ + lk8);
            gamn = Pbuf[cbn * T_ + T_ - 1];
        }

        // ---- stage B: acc = (K|Q) rows . (Shi + Slo) ----
        f32x4v accH = {0.f,0.f,0.f,0.f}, accL = {0.f,0.f,0.f,0.f};
#pragma unroll
        for (int ks = 0; ks < 4; ++ks) {
            bf16x8 hi = *(const bf16x8*)&Shi[lr * 136 + ks * 32 + lk8];
            bf16x8 lo = *(const bf16x8*)&Slo[lr * 136 + ks * 32 + lk8];
            accH = __builtin_amdgcn_mfma_f32_16x16x32_bf16(aF[ks], hi, accH, 0, 0, 0);
            accL = __builtin_amdgcn_mfma_f32_16x16x32_bf16(aF[ks], lo, accL, 0, 0, 0);
        }
        f32x4v accB;
#pragma unroll
        for (int j = 0; j < 4; ++j) accB[j] = accH[j] + accL[j];

        if (!isQ) {   // CT[d][t] = -C
            ushort4 cv;
            cv.x = f2bf(-accB[0]); cv.y = f2bf(-accB[1]);
            cv.z = f2bf(-accB[2]); cv.w = f2bf(-accB[3]);
            *(ushort4*)&CT[lr * 40 + mt * 16 + lrow4] = cv;
        }
        lds_barrier();

        // ---- stage D (waves 0,2): U = Ubar + What @ (-C) ----
        if (!isQ) {
            f32x4v accU;
#pragma unroll
            for (int j = 0; j < 4; ++j) accU[j] = sc4[j];
            bf16x8 bC = *(const bf16x8*)&CT[lr * 40 + lk8];
            accU = __builtin_amdgcn_mfma_f32_16x16x32_bf16(wmF, bC, accU, 0, 0, 0);
            ushort4 uv;
            uv.x = f2bf(accU[0]); uv.y = f2bf(accU[1]);
            uv.z = f2bf(accU[2]); uv.w = f2bf(accU[3]);
            *(ushort4*)&UT[lr * 40 + mt * 16 + lrow4] = uv;
        }
        lds_barrier();

        bf16x8 utF = *(const bf16x8*)&UT[lr * 40 + lk8];

        // ---- stage E (waves 1,3): O = diag(P)*accB + Mhat @ U ; write og ----
        if (isQ) {
            f32x4v accO;
#pragma unroll
            for (int j = 0; j < 4; ++j) accO[j] = sc4[j] * accB[j];
            accO = __builtin_amdgcn_mfma_f32_16x16x32_bf16(wmF, utF, accO, 0, 0, 0);
            const int tokb = c * T_ + mt * 16 + lrow4;
#pragma unroll
            for (int j = 0; j < 4; ++j)
                ogb[(size_t)(tokb + j) * INNER + d0 + lr] = f2bf(accO[j] * g4[j]);
        }

        // ---- stage F (all waves): S = gam*S + U^T @ Khat ; refresh hi/lo ----
#pragma unroll
        for (int j2 = 0; j2 < 2; ++j2) {
            const int et = 2 * w + j2;
            f32x4v accS;
#pragma unroll
            for (int j = 0; j < 4; ++j)
                accS[j] = gam * S[(lrow4 + j) * 132 + et * 16 + lr];
            accS = __builtin_amdgcn_mfma_f32_16x16x32_bf16(utF, khF[j2], accS, 0, 0, 0);
#pragma unroll
            for (int j = 0; j < 4; ++j) {
                float v = accS[j];
                S[(lrow4 + j) * 132 + et * 16 + lr] = v;
                unsigned short hh = f2bf(v);
                Shi[(lrow4 + j) * 136 + et * 16 + lr] = hh;
                Slo[(lrow4 + j) * 136 + et * 16 + lr] = f2bf(v - bf2f(hh));
            }
        }
        lds_barrier();

        // rotate prefetch registers
#pragma unroll
        for (int ks = 0; ks < 4; ++ks) aF[ks] = aFn[ks];
        wmF = wmFn;
#pragma unroll
        for (int j = 0; j < 4; ++j) { sc4[j] = sc4n[j]; g4[j] = g4n[j]; }
        khF[0] = khFn[0]; khF[1] = khFn[1];
        gam = gamn;
    }
}

extern "C" void kernel_launch(void* const* d_in, const int* in_sizes, int n_in,
                              void* d_out, int out_size, void* d_ws, size_t ws_size,
                              hipStream_t stream) {
    const float* x      = (const float*)d_in[0];
    const float* W_qkv  = (const float*)d_in[1];
    const float* conv_w = (const float*)d_in[2];
    const float* W_ab   = (const float*)d_in[3];
    const float* b_ab   = (const float*)d_in[4];
    const float* W_g    = (const float*)d_in[5];
    const float* W_o    = (const float*)d_in[6];
    float* out = (float*)d_out;

    char* p = (char*)d_ws;
    unsigned short* wqkvb   = (unsigned short*)p; p += (size_t)TRIPLE * DM * 2;
    unsigned short* wgb     = (unsigned short*)p; p += (size_t)INNER * DM * 2;
    unsigned short* wob     = (unsigned short*)p; p += (size_t)DM * INNER * 2;
    unsigned short* xb      = (unsigned short*)p; p += (size_t)M_ * DM * 2;
    unsigned short* qkv_pre = (unsigned short*)p; p += (size_t)M_ * TRIPLE * 2;
    unsigned short* qkv_c   = (unsigned short*)p; p += (size_t)M_ * TRIPLE * 2;
    float*          absig   = (float*)p;          p += (size_t)M_ * 32 * 4;
    float*          gpre    = (float*)p;          p += (size_t)M_ * INNER * 4;
    unsigned short* ogb     = (unsigned short*)p; p += (size_t)M_ * INNER * 2;

    // chunk buffers overlay xb+qkv_pre (dead after conv)
    char* q = (char*)xb;
    float*          Ubar  = (float*)q;          q += (size_t)32 * NCHK * T_ * HD * 4;
    unsigned short* KhatT = (unsigned short*)q; q += (size_t)32 * NCHK * HD * T_ * 2;
    unsigned short* What  = (unsigned short*)q; q += (size_t)32 * NCHK * T_ * T_ * 2;
    unsigned short* Mhat  = (unsigned short*)q; q += (size_t)32 * NCHK * T_ * T_ * 2;
    float*          Pbuf  = (float*)q;          q += (size_t)32 * NCHK * T_ * 4;

    dim3 blk(256);
    cast_bf16<<<dim3((M_ * DM) / 1024), blk, 0, stream>>>(x, xb, M_ * DM);
    cast_bf16<<<dim3((TRIPLE * DM) / 1024), blk, 0, stream>>>(W_qkv, wqkvb, TRIPLE * DM);
    cast_bf16<<<dim3((INNER * DM) / 1024), blk, 0, stream>>>(W_g, wgb, INNER * DM);
    cast_bf16<<<dim3((INNER * DM) / 1024), blk, 0, stream>>>(W_o, wob, INNER * DM);

    gemm_bf16<0, 1><<<dim3(TRIPLE / 128, M_ / 128), blk, 0, stream>>>(xb, wqkvb, qkv_pre, M_, TRIPLE, DM);
    gemm_bt_f32<<<dim3(1, M_ / 64), blk, 0, stream>>>(x, W_ab, b_ab, absig, M_, 32, DM, 2);
    gemm_bf16<1, 0><<<dim3(INNER / 128, M_ / 128), blk, 0, stream>>>(xb, wgb, gpre, M_, INNER, DM);
    conv_silu_norm<<<dim3(B_ * N_), blk, 0, stream>>>(qkv_pre, conv_w, qkv_c);

    chunk_prep<<<dim3(32 * NCHK), blk, 0, stream>>>(qkv_c, absig, Ubar, What, Mhat, KhatT, Pbuf);
    chunk_scan<<<dim3(256), blk, 0, stream>>>(qkv_c, gpre, Ubar, What, Mhat, KhatT, Pbuf, ogb);

    gemm_bf16<0, 0><<<dim3(INNER / 128, M_ / 128), blk, 0, stream>>>(ogb, wob, out, M_, INNER, DM);
}

// Round 9
// 677.130 us; speedup vs baseline: 9.5962x; 1.1210x over previous
//
#include <hip/hip_runtime.h>
#include <math.h>
#include <stddef.h>

#define B_ 2
#define N_ 2048
#define DM 2048
#define H_ 16
#define HD 128
#define INNER 2048
#define TRIPLE 6144
#define M_ (B_ * N_)   // 4096
#define T_ 32          // chunk length
#define NCHK (N_ / T_) // 64 chunks

typedef __bf16 bf16x8 __attribute__((ext_vector_type(8)));
typedef float  f32x4v __attribute__((ext_vector_type(4)));
typedef __attribute__((address_space(1))) const void gvoid;
typedef __attribute__((address_space(3))) void lvoid;

__device__ __forceinline__ float sig_(float x) { return 1.0f / (1.0f + __expf(-x)); }

__device__ __forceinline__ unsigned short f2bf(float f) {
    unsigned u = __float_as_uint(f);
    u += 0x7FFFu + ((u >> 16) & 1u);     // RNE
    return (unsigned short)(u >> 16);
}
__device__ __forceinline__ float bf2f(unsigned short h) {
    return __uint_as_float((unsigned)h << 16);
}
__device__ __forceinline__ void unpack8(uint4 r, float* f) {
    f[0] = __uint_as_float(r.x << 16); f[1] = __uint_as_float(r.x & 0xffff0000u);
    f[2] = __uint_as_float(r.y << 16); f[3] = __uint_as_float(r.y & 0xffff0000u);
    f[4] = __uint_as_float(r.z << 16); f[5] = __uint_as_float(r.z & 0xffff0000u);
    f[6] = __uint_as_float(r.w << 16); f[7] = __uint_as_float(r.w & 0xffff0000u);
}

// Workgroup barrier that waits ONLY on LDS ops (lgkmcnt(0)); prefetched
// global loads stay in flight across it.
__device__ __forceinline__ void lds_barrier() {
    asm volatile("" ::: "memory");
    __builtin_amdgcn_s_waitcnt(0xC07F);
    __builtin_amdgcn_s_barrier();
    asm volatile("" ::: "memory");
}

__global__ __launch_bounds__(256) void cast_bf16(
    const float* __restrict__ in, unsigned short* __restrict__ out, int n)
{
    int i = (blockIdx.x * 256 + threadIdx.x) * 4;
    if (i < n) {
        float4 v = *(const float4*)(in + i);
        out[i + 0] = f2bf(v.x); out[i + 1] = f2bf(v.y);
        out[i + 2] = f2bf(v.z); out[i + 3] = f2bf(v.w);
    }
}

// hi/lo split cast: hi = RNE-bf16(x), lo = bf16(x - hi)
__global__ __launch_bounds__(256) void cast_hilo(
    const float* __restrict__ in, unsigned short* __restrict__ hi,
    unsigned short* __restrict__ lo, int n)
{
    int i = (blockIdx.x * 256 + threadIdx.x) * 4;
    if (i < n) {
        float4 v = *(const float4*)(in + i);
        ushort4 h, l;
        h.x = f2bf(v.x); l.x = f2bf(v.x - bf2f(h.x));
        h.y = f2bf(v.y); l.y = f2bf(v.y - bf2f(h.y));
        h.z = f2bf(v.z); l.z = f2bf(v.z - bf2f(h.z));
        h.w = f2bf(v.w); l.w = f2bf(v.w - bf2f(h.w));
        *(ushort4*)(hi + i) = h;
        *(ushort4*)(lo + i) = l;
    }
}

// Fused (qkv | g) MFMA GEMM over concatenated weights [W_qkv; W_g] (8192 rows).
// Blocks with col0 < NQ write bf16 qkv; others write fp32 silu(g).
__global__ __launch_bounds__(256) void gemm_fused(
    const unsigned short* __restrict__ A, const unsigned short* __restrict__ Bw,
    unsigned short* __restrict__ outQ, float* __restrict__ outG,
    int M, int NQ, int NG, int K)
{
    __shared__ unsigned short As[128 * 32];
    __shared__ unsigned short Bs[128 * 32];
    const int tid  = threadIdx.x;
    const int w    = tid >> 6;
    const int l    = tid & 63;
    const int row0 = blockIdx.y * 128;
    const int col0 = blockIdx.x * 128;

    const int sr = tid >> 2;
    const int sc = (tid & 3) * 8;
    const unsigned short* Ag0 = A  + (size_t)(row0 + sr) * K + sc;
    const unsigned short* Ag1 = A  + (size_t)(row0 + 64 + sr) * K + sc;
    const unsigned short* Bg0 = Bw + (size_t)(col0 + sr) * K + sc;
    const unsigned short* Bg1 = Bw + (size_t)(col0 + 64 + sr) * K + sc;
    unsigned short* AsW0 = As + w * 512;
    unsigned short* AsW1 = As + 2048 + w * 512;
    unsigned short* BsW0 = Bs + w * 512;
    unsigned short* BsW1 = Bs + 2048 + w * 512;

    f32x4v acc[4][4];
#pragma unroll
    for (int i = 0; i < 4; ++i)
#pragma unroll
        for (int j = 0; j < 4; ++j) acc[i][j] = (f32x4v){0.f, 0.f, 0.f, 0.f};

    const int m0 = (w >> 1) * 64;
    const int n0 = (w & 1) * 64;
    const int lr = l & 15;
    const int lk = (l >> 4) * 8;

    for (int k0 = 0; k0 < K; k0 += 32) {
        __syncthreads();
        __builtin_amdgcn_global_load_lds((gvoid*)(Ag0 + k0), (lvoid*)AsW0, 16, 0, 0);
        __builtin_amdgcn_global_load_lds((gvoid*)(Ag1 + k0), (lvoid*)AsW1, 16, 0, 0);
        __builtin_amdgcn_global_load_lds((gvoid*)(Bg0 + k0), (lvoid*)BsW0, 16, 0, 0);
        __builtin_amdgcn_global_load_lds((gvoid*)(Bg1 + k0), (lvoid*)BsW1, 16, 0, 0);
        __syncthreads();

        bf16x8 af[4], bfr[4];
#pragma unroll
        for (int i = 0; i < 4; ++i) {
            af[i]  = *(const bf16x8*)&As[(m0 + i * 16 + lr) * 32 + lk];
            bfr[i] = *(const bf16x8*)&Bs[(n0 + i * 16 + lr) * 32 + lk];
        }
#pragma unroll
        for (int mi = 0; mi < 4; ++mi)
#pragma unroll
            for (int ni = 0; ni < 4; ++ni)
                acc[mi][ni] = __builtin_amdgcn_mfma_f32_16x16x32_bf16(
                    af[mi], bfr[ni], acc[mi][ni], 0, 0, 0);
    }

    const bool isG = (col0 >= NQ);   // block-uniform
#pragma unroll
    for (int mi = 0; mi < 4; ++mi) {
#pragma unroll
        for (int j = 0; j < 4; ++j) {
            int r = row0 + m0 + mi * 16 + (l >> 4) * 4 + j;
#pragma unroll
            for (int ni = 0; ni < 4; ++ni) {
                int c = col0 + n0 + ni * 16 + lr;
                float v = acc[mi][ni][j];
                if (!isG) {
                    outQ[(size_t)r * NQ + c] = f2bf(v);
                } else {
                    v = v * sig_(v);
                    outG[(size_t)r * NG + (c - NQ)] = v;
                }
            }
        }
    }
}

// Plain bf16 MFMA GEMM (fp32 out) — used for the final W_o projection.
__global__ __launch_bounds__(256) void gemm_bf16f(
    const unsigned short* __restrict__ A, const unsigned short* __restrict__ Bw,
    float* __restrict__ C, int M, int N, int K)
{
    __shared__ unsigned short As[128 * 32];
    __shared__ unsigned short Bs[128 * 32];
    const int tid  = threadIdx.x;
    const int w    = tid >> 6;
    const int l    = tid & 63;
    const int row0 = blockIdx.y * 128;
    const int col0 = blockIdx.x * 128;

    const int sr = tid >> 2;
    const int sc = (tid & 3) * 8;
    const unsigned short* Ag0 = A  + (size_t)(row0 + sr) * K + sc;
    const unsigned short* Ag1 = A  + (size_t)(row0 + 64 + sr) * K + sc;
    const unsigned short* Bg0 = Bw + (size_t)(col0 + sr) * K + sc;
    const unsigned short* Bg1 = Bw + (size_t)(col0 + 64 + sr) * K + sc;
    unsigned short* AsW0 = As + w * 512;
    unsigned short* AsW1 = As + 2048 + w * 512;
    unsigned short* BsW0 = Bs + w * 512;
    unsigned short* BsW1 = Bs + 2048 + w * 512;

    f32x4v acc[4][4];
#pragma unroll
    for (int i = 0; i < 4; ++i)
#pragma unroll
        for (int j = 0; j < 4; ++j) acc[i][j] = (f32x4v){0.f, 0.f, 0.f, 0.f};

    const int m0 = (w >> 1) * 64;
    const int n0 = (w & 1) * 64;
    const int lr = l & 15;
    const int lk = (l >> 4) * 8;

    for (int k0 = 0; k0 < K; k0 += 32) {
        __syncthreads();
        __builtin_amdgcn_global_load_lds((gvoid*)(Ag0 + k0), (lvoid*)AsW0, 16, 0, 0);
        __builtin_amdgcn_global_load_lds((gvoid*)(Ag1 + k0), (lvoid*)AsW1, 16, 0, 0);
        __builtin_amdgcn_global_load_lds((gvoid*)(Bg0 + k0), (lvoid*)BsW0, 16, 0, 0);
        __builtin_amdgcn_global_load_lds((gvoid*)(Bg1 + k0), (lvoid*)BsW1, 16, 0, 0);
        __syncthreads();

        bf16x8 af[4], bfr[4];
#pragma unroll
        for (int i = 0; i < 4; ++i) {
            af[i]  = *(const bf16x8*)&As[(m0 + i * 16 + lr) * 32 + lk];
            bfr[i] = *(const bf16x8*)&Bs[(n0 + i * 16 + lr) * 32 + lk];
        }
#pragma unroll
        for (int mi = 0; mi < 4; ++mi)
#pragma unroll
            for (int ni = 0; ni < 4; ++ni)
                acc[mi][ni] = __builtin_amdgcn_mfma_f32_16x16x32_bf16(
                    af[mi], bfr[ni], acc[mi][ni], 0, 0, 0);
    }

#pragma unroll
    for (int mi = 0; mi < 4; ++mi)
#pragma unroll
        for (int j = 0; j < 4; ++j) {
            int r = row0 + m0 + mi * 16 + (l >> 4) * 4 + j;
#pragma unroll
            for (int ni = 0; ni < 4; ++ni) {
                int c = col0 + n0 + ni * 16 + lr;
                C[(size_t)r * N + c] = acc[mi][ni][j];
            }
        }
}

// ab = sigmoid(x @ W_ab^T + b_ab) via split-bf16 MFMA (fp32-grade):
// x_hi*W_hi + x_hi*W_lo + x_lo*W_hi. Grid 64 blocks x 64 rows.
__global__ __launch_bounds__(256) void gemm_ab(
    const unsigned short* __restrict__ xhi, const unsigned short* __restrict__ xlo,
    const unsigned short* __restrict__ wh, const unsigned short* __restrict__ wl,
    const float* __restrict__ b_ab, float* __restrict__ absig)
{
    const int tid = threadIdx.x;
    const int w = tid >> 6, lane = tid & 63;
    const int lr = lane & 15, lk8 = (lane >> 4) * 8, lrow4 = (lane >> 4) * 4;
    const int row = blockIdx.x * 64 + w * 16 + lr;

    f32x4v acc[2];
    acc[0] = (f32x4v){0.f,0.f,0.f,0.f};
    acc[1] = (f32x4v){0.f,0.f,0.f,0.f};
    const unsigned short* Ah = xhi + (size_t)row * DM;
    const unsigned short* Al = xlo + (size_t)row * DM;

    for (int k0 = 0; k0 < DM; k0 += 32) {
        bf16x8 ah = *(const bf16x8*)(Ah + k0 + lk8);
        bf16x8 al = *(const bf16x8*)(Al + k0 + lk8);
#pragma unroll
        for (int nt = 0; nt < 2; ++nt) {
            bf16x8 whf = *(const bf16x8*)(wh + (size_t)(nt * 16 + lr) * DM + k0 + lk8);
            bf16x8 wlf = *(const bf16x8*)(wl + (size_t)(nt * 16 + lr) * DM + k0 + lk8);
            acc[nt] = __builtin_amdgcn_mfma_f32_16x16x32_bf16(ah, whf, acc[nt], 0, 0, 0);
            acc[nt] = __builtin_amdgcn_mfma_f32_16x16x32_bf16(ah, wlf, acc[nt], 0, 0, 0);
            acc[nt] = __builtin_amdgcn_mfma_f32_16x16x32_bf16(al, whf, acc[nt], 0, 0, 0);
        }
    }

    const int orow0 = blockIdx.x * 64 + w * 16 + lrow4;
#pragma unroll
    for (int nt = 0; nt < 2; ++nt) {
        int col = nt * 16 + lr;
        float bb = b_ab[col];
#pragma unroll
        for (int j = 0; j < 4; ++j)
            absig[(size_t)(orow0 + j) * 32 + col] = sig_(acc[nt][j] + bb);
    }
}

// conv(K=4, causal, depthwise) + silu + per-head l2norm of q,k.
// Vectorized bf16x8 IO; fp32 accumulation and norm.
__global__ __launch_bounds__(256) void conv_silu_norm(
    const unsigned short* __restrict__ qkv, const float* __restrict__ conv_w,
    unsigned short* __restrict__ outb)
{
    __shared__ float buf[TRIPLE];
    __shared__ float scales[32];
    const int bn = blockIdx.x;
    const int n = bn & (N_ - 1);
    const int tid = threadIdx.x;
    const unsigned short* base = qkv + (size_t)bn * TRIPLE;

#pragma unroll
    for (int it = 0; it < 3; ++it) {
        const int c8 = (tid + it * 256) * 8;
        float cw[32];
#pragma unroll
        for (int q4 = 0; q4 < 8; ++q4)
            *(float4*)&cw[q4 * 4] = *(const float4*)(conv_w + (size_t)c8 * 4 + q4 * 4);
        float acc[8] = {0.f,0.f,0.f,0.f,0.f,0.f,0.f,0.f};
#pragma unroll
        for (int j = 0; j < 4; ++j) {
            if (n - 3 + j >= 0) {
                uint4 r = *(const uint4*)(base + (ptrdiff_t)(j - 3) * TRIPLE + c8);
                float xf[8]; unpack8(r, xf);
#pragma unroll
                for (int e = 0; e < 8; ++e) acc[e] += xf[e] * cw[e * 4 + j];
            }
        }
        float4 o0, o1;
        o0.x = acc[0] * sig_(acc[0]); o0.y = acc[1] * sig_(acc[1]);
        o0.z = acc[2] * sig_(acc[2]); o0.w = acc[3] * sig_(acc[3]);
        o1.x = acc[4] * sig_(acc[4]); o1.y = acc[5] * sig_(acc[5]);
        o1.z = acc[6] * sig_(acc[6]); o1.w = acc[7] * sig_(acc[7]);
        *(float4*)&buf[c8] = o0;
        *(float4*)&buf[c8 + 4] = o1;
    }
    __syncthreads();

    const int g = tid >> 3, l = tid & 7;
    {
        int off = (g < 16) ? g * HD : 2048 + (g - 16) * HD;
        float s = 0.f;
        for (int i = l; i < HD; i += 8) { float v = buf[off + i]; s += v * v; }
        s += __shfl_xor(s, 1); s += __shfl_xor(s, 2); s += __shfl_xor(s, 4);
        if (l == 0) scales[g] = 1.0f / fmaxf(sqrtf(s), 1e-12f);
    }
    __syncthreads();

    unsigned short* ob = outb + (size_t)bn * TRIPLE;
#pragma unroll
    for (int it = 0; it < 3; ++it) {
        const int c8 = (tid + it * 256) * 8;
        float sc = 1.f;
        if (c8 < 2048) sc = scales[c8 >> 7];
        else if (c8 < 4096) sc = scales[16 + ((c8 - 2048) >> 7)];
        float4 f0 = *(const float4*)&buf[c8];
        float4 f1 = *(const float4*)&buf[c8 + 4];
        ushort4 u0, u1;
        u0.x = f2bf(f0.x * sc); u0.y = f2bf(f0.y * sc);
        u0.z = f2bf(f0.z * sc); u0.w = f2bf(f0.w * sc);
        u1.x = f2bf(f1.x * sc); u1.y = f2bf(f1.y * sc);
        u1.z = f2bf(f1.z * sc); u1.w = f2bf(f1.w * sc);
        *(ushort4*)(ob + c8) = u0;
        *(ushort4*)(ob + c8 + 4) = u1;
    }
}

// ---------------- chunked delta rule ----------------
__global__ __launch_bounds__(256) void chunk_prep(
    const unsigned short* __restrict__ qkvc, const float* __restrict__ absig,
    float* __restrict__ Ubar, unsigned short* __restrict__ What,
    unsigned short* __restrict__ Mhat, unsigned short* __restrict__ KhatT,
    float* __restrict__ Pbuf)
{
    __shared__ float G[T_], Pl[T_], Bl[T_];
    __shared__ float L[T_][T_ + 1];
    __shared__ float X[T_][161];
    const int bh = blockIdx.x >> 6;
    const int c  = blockIdx.x & 63;
    const int b  = bh >> 4;
    const int h  = bh & 15;
    const int tid = threadIdx.x;
    const int tok0 = c * T_;
    const size_t qbase = (size_t)b * N_ * TRIPLE;
    const unsigned short* Kb = qkvc + qbase + 2048 + h * HD;
    const unsigned short* Qb = qkvc + qbase + h * HD;
    const unsigned short* Vb = qkvc + qbase + 4096 + h * HD;
    const float* abb = absig + (size_t)b * N_ * 32;

    if (tid < T_) {
        G[tid]  = __logf(abb[(tok0 + tid) * 32 + h]);
        Bl[tid] = abb[(tok0 + tid) * 32 + 16 + h];
    }
    __syncthreads();
    if (tid == 0) {
        float run = 0.f;
        for (int t = 0; t < T_; ++t) { run += G[t]; G[t] = run; Pl[t] = __expf(run); }
    }
    __syncthreads();
    if (tid < T_) Pbuf[((size_t)bh * NCHK + c) * T_ + tid] = Pl[tid];

    const int w = tid >> 6, lane = tid & 63;
    const int lr = lane & 15, lk8 = (lane >> 4) * 8, lrow4 = (lane >> 4) * 4;
    const int mt = w >> 1, nt = w & 1;

    f32x4v akk = {0.f,0.f,0.f,0.f}, aqk = {0.f,0.f,0.f,0.f};
    const unsigned short* Km = Kb + (size_t)(tok0 + mt * 16 + lr) * TRIPLE;
    const unsigned short* Qm = Qb + (size_t)(tok0 + mt * 16 + lr) * TRIPLE;
    const unsigned short* Kn = Kb + (size_t)(tok0 + nt * 16 + lr) * TRIPLE;
#pragma unroll
    for (int ks = 0; ks < 4; ++ks) {
        bf16x8 aK = *(const bf16x8*)(Km + ks * 32 + lk8);
        bf16x8 aQ = *(const bf16x8*)(Qm + ks * 32 + lk8);
        bf16x8 bK = *(const bf16x8*)(Kn + ks * 32 + lk8);
        akk = __builtin_amdgcn_mfma_f32_16x16x32_bf16(aK, bK, akk, 0, 0, 0);
        aqk = __builtin_amdgcn_mfma_f32_16x16x32_bf16(aQ, bK, aqk, 0, 0, 0);
    }
    unsigned short* Mg = Mhat + ((size_t)bh * NCHK + c) * (T_ * T_);
#pragma unroll
    for (int reg = 0; reg < 4; ++reg) {
        int t = mt * 16 + lrow4 + reg;
        int i = nt * 16 + lr;
        float dec = __expf(G[t] - G[i]);
        L[t][i] = (i < t) ? Bl[t] * dec * akk[reg] : 0.f;
        Mg[t * T_ + i] = (i <= t) ? f2bf(dec * aqk[reg]) : (unsigned short)0;
    }
    __syncthreads();

    for (int idx = tid; idx < T_ * HD; idx += 256) {
        int t = idx >> 7, e = idx & 127;
        X[t][e] = Bl[t] * bf2f(Vb[(size_t)(tok0 + t) * TRIPLE + e]);
    }
    for (int idx = tid; idx < T_ * T_; idx += 256) {
        int t = idx >> 5, i = idx & 31;
        X[t][HD + i] = (i == t) ? Bl[t] * Pl[t] : 0.f;
    }
    __syncthreads();

    if (tid < HD + T_) {
        float x[T_];
#pragma unroll
        for (int t = 0; t < T_; ++t) x[t] = X[t][tid];
#pragma unroll
        for (int t = 1; t < T_; ++t)
#pragma unroll
            for (int i = 0; i < t; ++i)
                x[t] -= L[t][i] * x[i];
        if (tid < HD) {
            float* Ug = Ubar + ((size_t)bh * NCHK + c) * (T_ * HD);
#pragma unroll
            for (int t = 0; t < T_; ++t) Ug[t * HD + tid] = x[t];
        } else {
            unsigned short* Wg = What + ((size_t)bh * NCHK + c) * (T_ * T_);
#pragma unroll
            for (int t = 0; t < T_; ++t) Wg[t * T_ + (tid - HD)] = f2bf(x[t]);
        }
    }

    unsigned short* Kg = KhatT + ((size_t)bh * NCHK + c) * (HD * T_);
    for (int idx = tid; idx < HD * T_; idx += 256) {
        int e = idx >> 5, t = idx & 31;
        float v = __expf(G[T_ - 1] - G[t]) * bf2f(Kb[(size_t)(tok0 + t) * TRIPLE + e]);
        Kg[idx] = f2bf(v);
    }
}

// Serial phase (as R8): 256 blocks = 32 bh x 8 d-slices of 16 rows.
__global__ __launch_bounds__(256) void chunk_scan(
    const unsigned short* __restrict__ qkvc, const float* __restrict__ gpre,
    const float* __restrict__ Ubar, const unsigned short* __restrict__ What,
    const unsigned short* __restrict__ Mhat, const unsigned short* __restrict__ KhatT,
    const float* __restrict__ Pbuf, unsigned short* __restrict__ og)
{
    __shared__ float          S  [16 * 132];
    __shared__ unsigned short Shi[16 * 136];
    __shared__ unsigned short Slo[16 * 136];
    __shared__ unsigned short CT [16 * 40];
    __shared__ unsigned short UT [16 * 40];

    const int blk = blockIdx.x;
    const int bh  = blk & 31;
    const int dsl = blk >> 5;
    const int b = bh >> 4, h = bh & 15;
    const int d0 = dsl * 16;
    const int tid = threadIdx.x;
    const int w = tid >> 6, lane = tid & 63;
    const int lr = lane & 15, lk8 = (lane >> 4) * 8, lrow4 = (lane >> 4) * 4;
    const int mt = w >> 1;
    const bool isQ = (w & 1);

    for (int i = tid; i < 16 * 132; i += 256) S[i] = 0.f;
    for (int i = tid; i < 16 * 136; i += 256) { Shi[i] = 0; Slo[i] = 0; }

    const size_t qbase = (size_t)b * N_ * TRIPLE;
    const unsigned short* Ab = qkvc + qbase + (isQ ? 0 : 2048) + h * HD;
    const float* gb = gpre + (size_t)b * N_ * INNER + h * HD;
    unsigned short* ogb = og + (size_t)b * N_ * INNER + h * HD;

    bf16x8 aF[4];
    bf16x8 wmF;
    float  sc4[4];
    float  g4[4];
    bf16x8 khF[2];
    float  gam;
    {
        const size_t cb = (size_t)bh * NCHK;
        const unsigned short* Am = Ab + (size_t)(mt * 16 + lr) * TRIPLE;
#pragma unroll
        for (int ks = 0; ks < 4; ++ks) aF[ks] = *(const bf16x8*)(Am + ks * 32 + lk8);
        if (!isQ) {
            wmF = *(const bf16x8*)(What + cb * (T_*T_) + (mt * 16 + lr) * T_ + lk8);
#pragma unroll
            for (int j = 0; j < 4; ++j)
                sc4[j] = Ubar[cb * (T_*HD) + (mt * 16 + lrow4 + j) * HD + d0 + lr];
        } else {
            wmF = *(const bf16x8*)(Mhat + cb * (T_*T_) + (mt * 16 + lr) * T_ + lk8);
#pragma unroll
            for (int j = 0; j < 4; ++j) {
                sc4[j] = Pbuf[cb * T_ + mt * 16 + lrow4 + j];
                g4[j]  = gb[(size_t)(mt * 16 + lrow4 + j) * INNER + d0 + lr];
            }
        }
#pragma unroll
        for (int j2 = 0; j2 < 2; ++j2)
            khF[j2] = *(const bf16x8*)(KhatT + cb * (HD*T_) + ((2*w + j2) * 16 + lr) * T_ + lk8);
        gam = Pbuf[cb * T_ + T_ - 1];
    }
    __syncthreads();

    for (int c = 0; c < NCHK; ++c) {
        const int np = (c + 1 < NCHK) ? c + 1 : c;
        const size_t cbn = (size_t)bh * NCHK + np;
        const int tok0n = np * T_;
        bf16x8 aFn[4], wmFn, khFn[2];
        float sc4n[4], g4n[4], gamn;
        {
            const unsigned short* Am = Ab + (size_t)(tok0n + mt * 16 + lr) * TRIPLE;
#pragma unroll
            for (int ks = 0; ks < 4; ++ks) aFn[ks] = *(const bf16x8*)(Am + ks * 32 + lk8);
            if (!isQ) {
                wmFn = *(const bf16x8*)(What + cbn * (T_*T_) + (mt * 16 + lr) * T_ + lk8);
#pragma unroll
                for (int j = 0; j < 4; ++j)
                    sc4n[j] = Ubar[cbn * (T_*HD) + (mt * 16 + lrow4 + j) * HD + d0 + lr];
            } else {
                wmFn = *(const bf16x8*)(Mhat + cbn * (T_*T_) + (mt * 16 + lr) * T_ + lk8);
#pragma unroll
                for (int j = 0; j < 4; ++j) {
                    sc4n[j] = Pbuf[cbn * T_ + mt * 16 + lrow4 + j];
                    g4n[j]  = gb[(size_t)(tok0n + mt * 16 + lrow4 + j) * INNER + d0 + lr];
                }
            }
#pragma unroll
            for (int j2 = 0; j2 < 2; ++j2)
                khFn[j2] = *(const bf16x8*)(KhatT + cbn * (HD*T_) + ((2*w + j2) * 16 + lr) * T_ + lk8);
            gamn = Pbuf[cbn * T_ + T_ - 1];
        }

        f32x4v accH = {0.f,0.f,0.f,0.f}, accL = {0.f,0.f,0.f,0.f};
#pragma unroll
        for (int ks = 0; ks < 4; ++ks) {
            bf16x8 hi = *(const bf16x8*)&Shi[lr * 136 + ks * 32 + lk8];
            bf16x8 lo = *(const bf16x8*)&Slo[lr * 136 + ks * 32 + lk8];
            accH = __builtin_amdgcn_mfma_f32_16x16x32_bf16(aF[ks], hi, accH, 0, 0, 0);
            accL = __builtin_amdgcn_mfma_f32_16x16x32_bf16(aF[ks], lo, accL, 0, 0, 0);
        }
        f32x4v accB;
#pragma unroll
        for (int j = 0; j < 4; ++j) accB[j] = accH[j] + accL[j];

        if (!isQ) {
            ushort4 cv;
            cv.x = f2bf(-accB[0]); cv.y = f2bf(-accB[1]);
            cv.z = f2bf(-accB[2]); cv.w = f2bf(-accB[3]);
            *(ushort4*)&CT[lr * 40 + mt * 16 + lrow4] = cv;
        }
        lds_barrier();

        if (!isQ) {
            f32x4v accU;
#pragma unroll
            for (int j = 0; j < 4; ++j) accU[j] = sc4[j];
            bf16x8 bC = *(const bf16x8*)&CT[lr * 40 + lk8];
            accU = __builtin_amdgcn_mfma_f32_16x16x32_bf16(wmF, bC, accU, 0, 0, 0);
            ushort4 uv;
            uv.x = f2bf(accU[0]); uv.y = f2bf(accU[1]);
            uv.z = f2bf(accU[2]); uv.w = f2bf(accU[3]);
            *(ushort4*)&UT[lr * 40 + mt * 16 + lrow4] = uv;
        }
        lds_barrier();

        bf16x8 utF = *(const bf16x8*)&UT[lr * 40 + lk8];

        if (isQ) {
            f32x4v accO;
#pragma unroll
            for (int j = 0; j < 4; ++j) accO[j] = sc4[j] * accB[j];
            accO = __builtin_amdgcn_mfma_f32_16x16x32_bf16(wmF, utF, accO, 0, 0, 0);
            const int tokb = c * T_ + mt * 16 + lrow4;
#pragma unroll
            for (int j = 0; j < 4; ++j)
                ogb[(size_t)(tokb + j) * INNER + d0 + lr] = f2bf(accO[j] * g4[j]);
        }

#pragma unroll
        for (int j2 = 0; j2 < 2; ++j2) {
            const int et = 2 * w + j2;
            f32x4v accS;
#pragma unroll
            for (int j = 0; j < 4; ++j)
                accS[j] = gam * S[(lrow4 + j) * 132 + et * 16 + lr];
            accS = __builtin_amdgcn_mfma_f32_16x16x32_bf16(utF, khF[j2], accS, 0, 0, 0);
#pragma unroll
            for (int j = 0; j < 4; ++j) {
                float v = accS[j];
                S[(lrow4 + j) * 132 + et * 16 + lr] = v;
                unsigned short hh = f2bf(v);
                Shi[(lrow4 + j) * 136 + et * 16 + lr] = hh;
                Slo[(lrow4 + j) * 136 + et * 16 + lr] = f2bf(v - bf2f(hh));
            }
        }
        lds_barrier();

#pragma unroll
        for (int ks = 0; ks < 4; ++ks) aF[ks] = aFn[ks];
        wmF = wmFn;
#pragma unroll
        for (int j = 0; j < 4; ++j) { sc4[j] = sc4n[j]; g4[j] = g4n[j]; }
        khF[0] = khFn[0]; khF[1] = khFn[1];
        gam = gamn;
    }
}

extern "C" void kernel_launch(void* const* d_in, const int* in_sizes, int n_in,
                              void* d_out, int out_size, void* d_ws, size_t ws_size,
                              hipStream_t stream) {
    const float* x      = (const float*)d_in[0];
    const float* W_qkv  = (const float*)d_in[1];
    const float* conv_w = (const float*)d_in[2];
    const float* W_ab   = (const float*)d_in[3];
    const float* b_ab   = (const float*)d_in[4];
    const float* W_g    = (const float*)d_in[5];
    const float* W_o    = (const float*)d_in[6];
    float* out = (float*)d_out;

    // Workspace layout. wqkvb and wgb MUST be contiguous (fused GEMM treats
    // them as one 8192-row weight matrix). Total ~227 MB.
    char* p = (char*)d_ws;
    unsigned short* wqkvb   = (unsigned short*)p; p += (size_t)TRIPLE * DM * 2;
    unsigned short* wgb     = (unsigned short*)p; p += (size_t)INNER * DM * 2;   // contiguous!
    unsigned short* wob     = (unsigned short*)p; p += (size_t)DM * INNER * 2;
    unsigned short* wabhi   = (unsigned short*)p; p += (size_t)32 * DM * 2;
    unsigned short* wablo   = (unsigned short*)p; p += (size_t)32 * DM * 2;
    unsigned short* xb      = (unsigned short*)p; p += (size_t)M_ * DM * 2;
    unsigned short* xlo     = (unsigned short*)p; p += (size_t)M_ * DM * 2;
    unsigned short* qkv_pre = (unsigned short*)p; p += (size_t)M_ * TRIPLE * 2;
    unsigned short* qkv_c   = (unsigned short*)p; p += (size_t)M_ * TRIPLE * 2;
    float*          absig   = (float*)p;          p += (size_t)M_ * 32 * 4;
    float*          gpre    = (float*)p;          p += (size_t)M_ * INNER * 4;
    unsigned short* ogb     = (unsigned short*)p; p += (size_t)M_ * INNER * 2;

    // chunk buffers overlay xb..qkv_pre (dead after gemm_ab / conv)
    char* q = (char*)xb;
    float*          Ubar  = (float*)q;          q += (size_t)32 * NCHK * T_ * HD * 4;
    unsigned short* KhatT = (unsigned short*)q; q += (size_t)32 * NCHK * HD * T_ * 2;
    unsigned short* What  = (unsigned short*)q; q += (size_t)32 * NCHK * T_ * T_ * 2;
    unsigned short* Mhat  = (unsigned short*)q; q += (size_t)32 * NCHK * T_ * T_ * 2;
    float*          Pbuf  = (float*)q;          q += (size_t)32 * NCHK * T_ * 4;

    dim3 blk(256);
    cast_hilo<<<dim3((M_ * DM) / 1024), blk, 0, stream>>>(x, xb, xlo, M_ * DM);
    cast_bf16<<<dim3((TRIPLE * DM) / 1024), blk, 0, stream>>>(W_qkv, wqkvb, TRIPLE * DM);
    cast_bf16<<<dim3((INNER * DM) / 1024), blk, 0, stream>>>(W_g, wgb, INNER * DM);
    cast_bf16<<<dim3((INNER * DM) / 1024), blk, 0, stream>>>(W_o, wob, INNER * DM);
    cast_hilo<<<dim3((32 * DM) / 1024), blk, 0, stream>>>(W_ab, wabhi, wablo, 32 * DM);

    // fused: qkv (bf16) + g (fp32 silu)
    gemm_fused<<<dim3((TRIPLE + INNER) / 128, M_ / 128), blk, 0, stream>>>(
        xb, wqkvb, qkv_pre, gpre, M_, TRIPLE, INNER, DM);
    // ab (split-bf16, fp32-grade) + sigmoid
    gemm_ab<<<dim3(M_ / 64), blk, 0, stream>>>(xb, xlo, wabhi, wablo, b_ab, absig);
    // conv + silu + l2norm (vectorized)
    conv_silu_norm<<<dim3(B_ * N_), blk, 0, stream>>>(qkv_pre, conv_w, qkv_c);

    chunk_prep<<<dim3(32 * NCHK), blk, 0, stream>>>(qkv_c, absig, Ubar, What, Mhat, KhatT, Pbuf);
    chunk_scan<<<dim3(256), blk, 0, stream>>>(qkv_c, gpre, Ubar, What, Mhat, KhatT, Pbuf, ogb);

    gemm_bf16f<<<dim3(INNER / 128, M_ / 128), blk, 0, stream>>>(ogb, wob, out, M_, INNER, DM);
}